// Round 7
// baseline (211.007 us; speedup 1.0000x reference)
//
#include <hip/hip_runtime.h>

// FocalSelfAttention on MI355X. fp32 I/O, bf16 MFMA compute, fp32 accum.
// B=4, C=128, H=W=48, WS=4 -> 144 windows/batch, 16 q/window, NH=8, hd=16,
// Nkv = 64 local + 720 pooled.
//
// v15: barrier-free attn main loop via WAVE-PRIVATE K staging.
// v14 diagnosis: VALU work ~15us, kernel 54us -> 70% stall; each of 12
// rounds ends vmcnt->ds_write->__syncthreads aligning all 8 waves on a
// ~600-900cy cross-XCD first-touch latency. Fix: each wave stages only its
// head's 32B column slice of the K tile (lane l <- K[rbase+l][wave*16..+15],
// 2x dwordx4, disjoint across waves -> no duplication) into a wave-private
// double-buffered KP[wave][2][64][16]. DS ops are in-order per wave -> NO
// block barrier in the loop (2 barriers total, for the At/VtW overlay).
// Plus: V-fragment prefetch 1 tile ahead (rolling named regs, SSA-safe) and
// F-residual prefetch after the early barrier (removes exposed cold read at
// the epilogue). LDS 67.6 KB -> 2 blocks/CU.
// prep_gemm unchanged from v14 (delta stays attributable to attn).

typedef unsigned short u16;
typedef short v8s __attribute__((ext_vector_type(8)));
typedef v8s __attribute__((may_alias)) v8s_am;
typedef short v4s __attribute__((ext_vector_type(4)));
typedef v4s __attribute__((may_alias)) v4s_am;
typedef float v4f __attribute__((ext_vector_type(4)));

#define MFMA_BF16(a, b, c) __builtin_amdgcn_mfma_f32_16x16x32_bf16(a, b, c, 0, 0, 0)

#if __has_builtin(__builtin_amdgcn_mfma_f32_16x16x16bf16_1k)
#define MFMA16(a, b, c) __builtin_amdgcn_mfma_f32_16x16x16bf16_1k(a, b, c, 0, 0, 0)
#else
static __device__ __forceinline__ v4f mfma16_fb(v4s a, v4s b, v4f c) {
    v8s a8 = {a[0], a[1], a[2], a[3], 0, 0, 0, 0};
    v8s b8 = {b[0], b[1], b[2], b[3], 0, 0, 0, 0};
    return MFMA_BF16(a8, b8, c);
}
#define MFMA16(a, b, c) mfma16_fb(a, b, c)
#endif

#if __has_builtin(__builtin_amdgcn_exp2f)
#define EXP2(x) __builtin_amdgcn_exp2f(x)
#else
#define EXP2(x) exp2f(x)
#endif

__device__ __forceinline__ float b2f(u16 u) {
    union { unsigned int i; float f; } x;
    x.i = ((unsigned int)u) << 16;
    return x.f;
}
__device__ __forceinline__ u16 f2b(float f) {
    union { float f; unsigned int i; } x;
    x.f = f;
    unsigned int u = x.i;
    return (u16)((u + 0x7fffu + ((u >> 16) & 1u)) >> 16);
}

__device__ __forceinline__ int rbase_of(int b, int tb) {
    return (tb < 9) ? (b * 576 + tb * 64) : (2304 + b * 144 + (tb - 9) * 64);
}

// ---------------------------------------------------------------------------
// Kernel 1 (merged prep + pooled K/V GEMM), 484 blocks x 256 (v14, unchanged)
__global__ __launch_bounds__(256) void k_prep_gemm(
    const float* __restrict__ F,
    const float* __restrict__ qw, const float* __restrict__ kvw,
    const float* __restrict__ ow,
    const float* __restrict__ lnw, const float* __restrict__ lnb,
    const float* __restrict__ kvb,
    u16* __restrict__ Xt, u16* __restrict__ Wb, float* __restrict__ MuRs,
    u16* __restrict__ KVg, u16* __restrict__ VTg)
{
    __shared__ u16 SH[17408];    // 34.8 KB, aliased per block range
    int blk = blockIdx.x;
    int t = threadIdx.x;

    if (blk >= 304) {
        // ---- pooled K/V GEMM: 180 blocks (45 tm x 4 tn) ----
        u16 (*Al)[136] = (u16(*)[136])SH;          // [64][136]
        u16 (*Wl)[136] = (u16(*)[136])(SH + 8704); // [64][136]
        int gb = blk - 304;
        int tm = (gb % 45) * 64, tn = (gb / 45) * 64;
        {
            int seg = t & 15, r0 = t >> 4;
#pragma unroll
            for (int i = 0; i < 4; ++i) {
                int r = r0 + 16 * i;
                const float* src = kvw + (size_t)(tn + r) * 128 + seg * 8;
                float4 v0 = *(const float4*)src;
                float4 v1 = *(const float4*)(src + 4);
                v8s o = {(short)f2b(v0.x), (short)f2b(v0.y), (short)f2b(v0.z), (short)f2b(v0.w),
                         (short)f2b(v1.x), (short)f2b(v1.y), (short)f2b(v1.z), (short)f2b(v1.w)};
                *(v8s_am*)&Wl[r][seg * 8] = o;
            }
        }
        {
            int rs = t >> 2;             // token slot 0..63
            int cp = (t & 3) * 32;       // channel group
            int m = tm + rs;
            float s[32];
            if (m < 2304) {              // mid: avg 2x2
                int bb = m / 576, loc = m % 576;
                int ii = loc / 24, jj2 = loc % 24;
                const float* f0 = F + (size_t)(bb * 128 + cp) * 2304 + (2 * ii) * 48 + 2 * jj2;
#pragma unroll
                for (int cc = 0; cc < 32; ++cc) {
                    const float* src = f0 + (size_t)cc * 2304;
                    float2 a = *(const float2*)src;
                    float2 d = *(const float2*)(src + 48);
                    s[cc] = (a.x + a.y + d.x + d.y) * 0.25f;
                }
            } else {                     // glo: avg 4x4
                int r2 = m - 2304;
                int bb = r2 / 144, loc = r2 % 144;
                int ii = loc / 12, jj2 = loc % 12;
                const float* f0 = F + (size_t)(bb * 128 + cp) * 2304 + (4 * ii) * 48 + 4 * jj2;
#pragma unroll
                for (int cc = 0; cc < 32; ++cc) {
                    const float* src = f0 + (size_t)cc * 2304;
                    float ss = 0.f;
#pragma unroll
                    for (int di = 0; di < 4; ++di) {
                        float4 v = *(const float4*)(src + di * 48);
                        ss += (v.x + v.y) + (v.z + v.w);
                    }
                    s[cc] = ss * 0.0625f;
                }
            }
#pragma unroll
            for (int k = 0; k < 4; ++k) {
                v8s o;
#pragma unroll
                for (int jj = 0; jj < 8; ++jj) o[jj] = (short)f2b(s[k * 8 + jj]);
                *(v8s_am*)&Al[rs][cp + k * 8] = o;
            }
        }
        __syncthreads();
        int lane = t & 63, wave = t >> 6;
        int n15 = lane & 15, quad = lane >> 4;
        int wm = (wave & 1) * 32, wn = (wave >> 1) * 32;
        v4f acc[2][2] = {};
#pragma unroll
        for (int kc = 0; kc < 4; ++kc) {
            v8s a[2], bb[2];
#pragma unroll
            for (int im = 0; im < 2; ++im)
                a[im] = *(const v8s_am*)&Al[wm + im * 16 + n15][kc * 32 + quad * 8];
#pragma unroll
            for (int in = 0; in < 2; ++in)
                bb[in] = *(const v8s_am*)&Wl[wn + in * 16 + n15][kc * 32 + quad * 8];
#pragma unroll
            for (int im = 0; im < 2; ++im)
#pragma unroll
                for (int in = 0; in < 2; ++in)
                    acc[im][in] = MFMA_BF16(a[im], bb[in], acc[im][in]);
        }
        bool vblk = (tn >= 128);
        bool vfast = vblk && (tm < 2304);        // block-uniform
        u16* vt = &Al[0][0];                     // overlay [64 ch][72 tok]
        if (vfast) __syncthreads();              // Al reads done before overlay
#pragma unroll
        for (int in = 0; in < 2; ++in) {
            int n = tn + wn + in * 16 + n15;
            float bv = kvb[n];
#pragma unroll
            for (int im = 0; im < 2; ++im) {
                int mbase = tm + wm + im * 16 + quad * 4;
#pragma unroll
                for (int r = 0; r < 4; ++r) {
                    int m = mbase + r;
                    u16 h = f2b(acc[im][in][r] + bv);
                    if (!vblk) {
                        KVg[((size_t)m) * 128 + n] = h;
                    } else if (vfast) {
                        vt[(n - tn) * 72 + (wm + im * 16 + quad * 4 + r)] = h;
                    } else {
                        int ch = n - 128;
                        int r2 = m - 2304;
                        int bb2 = r2 / 144, tok = 576 + r2 % 144;
                        VTg[((size_t)(bb2 * 128 + ch)) * 720 + tok] = h;
                    }
                }
            }
        }
        if (vfast) {
            __syncthreads();
            int ch = t >> 2, seg = t & 3;
            int bb2 = tm / 576, tokbase = tm % 576;
            v8s a0 = *(const v8s_am*)&vt[ch * 72 + seg * 16];
            v8s a1 = *(const v8s_am*)&vt[ch * 72 + seg * 16 + 8];
            size_t d = ((size_t)(bb2 * 128 + (tn - 128) + ch)) * 720 + tokbase + seg * 16;
            *(v8s_am*)&VTg[d]     = a0;
            *(v8s_am*)&VTg[d + 8] = a1;
        }
        return;
    }
    if (blk >= 288) {   // ---- weight conversion: 16 blocks ----
        int base = (blk - 288) * 4096 + t * 16;
#pragma unroll
        for (int i = 0; i < 4; ++i) {
            int idx = base + i * 4;
            const float* src; int off;
            if (idx < 16384)      { src = qw;  off = idx; }
            else if (idx < 49152) { src = kvw; off = idx - 16384; }
            else                  { src = ow;  off = idx - 49152; }
            float4 v = *(const float4*)(src + off);
            unsigned long long packed =
                (unsigned long long)f2b(v.x) |
                ((unsigned long long)f2b(v.y) << 16) |
                ((unsigned long long)f2b(v.z) << 32) |
                ((unsigned long long)f2b(v.w) << 48);
            *(unsigned long long*)(Wb + idx) = packed;
        }
        if (blk == 288) {   // ln params -> bf16 at Wb+65536
            Wb[65536 + t] = f2b(t < 128 ? lnw[t] : lnb[t - 128]);
        }
        return;
    }
    // ---- transpose + LN stats: 288 blocks ----
    u16 (*X)[34] = (u16(*)[34])SH;   // [128][34]
    int b = blk / 72;
    int p0 = (blk % 72) * 32;
#pragma unroll 4
    for (int i = 0; i < 16; ++i) {
        int c = i * 8 + (t >> 5);
        int pix = t & 31;
        X[c][pix] = f2b(F[((size_t)(b * 128 + c)) * 2304 + p0 + pix]);
    }
    __syncthreads();
    int pix = t >> 3;
    int c0 = (t & 7) * 16;
    size_t row = (size_t)(b * 2304 + p0 + pix) * 128;
    float s = 0.f, s2 = 0.f;
#pragma unroll
    for (int sg = 0; sg < 2; ++sg) {
        v8s raw;
#pragma unroll
        for (int j = 0; j < 8; ++j) {
            u16 u = X[c0 + sg * 8 + j][pix];
            raw[j] = (short)u;
            float v = b2f(u);
            s += v; s2 += v * v;
        }
        *(v8s_am*)&Xt[row + c0 + sg * 8] = raw;
    }
    s += __shfl_xor(s, 1);  s2 += __shfl_xor(s2, 1);
    s += __shfl_xor(s, 2);  s2 += __shfl_xor(s2, 2);
    s += __shfl_xor(s, 4);  s2 += __shfl_xor(s2, 4);
    if ((t & 7) == 0) {
        float mean = s * (1.f / 128.f);
        float var = s2 * (1.f / 128.f) - mean * mean;
        float rstd = rsqrtf(var + 1e-5f);
        MuRs[(b * 2304 + p0 + pix) * 2]     = mean;
        MuRs[(b * 2304 + p0 + pix) * 2 + 1] = rstd;
    }
}

// ---------------------------------------------------------------------------
// Kernel 2: fused attention, 2 windows per block. 288 blocks x 512 thr
// (8 waves), wave w = head w for both windows. Barrier-free main loop with
// wave-private double-buffered K staging + V prefetch. 2 barriers total.
__global__ __launch_bounds__(512, 4) void k_attn_fused(
    const float* __restrict__ F,
    const u16* __restrict__ Xt,
    const float* __restrict__ MuRs,
    const u16* __restrict__ KVg,
    const u16* __restrict__ VTg,
    const u16* __restrict__ Wb,     // [qwb|kvwb|owb|lnwb|lnbb]
    const float* __restrict__ qb,
    const float* __restrict__ kvb,
    const float* __restrict__ ob,
    float* __restrict__ Out)
{
    __shared__ u16 KP[8][2][64][16];    // wave-private K slices, dbuf (32 KB)
    __shared__ u16 VtW[8][2][16][68];   // per-wave/window local V^T (34.8 KB)

    const u16* qwb  = Wb;
    const u16* kvwb = Wb + 16384;
    const u16* owb  = Wb + 49152;
    const u16* lnwb = Wb + 65536;
    const u16* lnbb = Wb + 65664;
    u16* Atp = &VtW[0][0][0][0];        // overlay [2][16][136] = 4352 u16

    // Bijective XCD swizzle: 288 = 8 xcd x 36. xcd -> one batch-half.
    int blk = blockIdx.x;
    int xcd = blk & 7, jj = blk >> 3;   // jj 0..35
    int b = xcd >> 1;
    int wr = (xcd & 1) * 6 + jj / 6;
    int wcp = jj % 6;                   // window-pair; windows wc=2*wcp+{0,1}

    int t = threadIdx.x;
    int lane = t & 63, wave = t >> 6, n15 = lane & 15, quad = lane >> 4;
    v8s zf8 = {};
    v4f zz4 = {0.f, 0.f, 0.f, 0.f};
    const float QSCALE = 0.25f * 1.44269504f;

    u16* KPw = &KP[wave][0][0][0];      // buffers at +0 / +1024 (u16)
    const u16* kvcol = KVg + wave * 16;
    const u16* vrow0 = VTg + (size_t)b * 92160
                     + (size_t)(wave * 16 + n15) * 720 + quad * 4;

    // --- issue tile-0 K slice + V fragments immediately ---
    v8s kC0, kC1;
    {
        const u16* s = kvcol + (size_t)(b * 576 + lane) * 128;
        kC0 = *(const v8s_am*)s; kC1 = *(const v8s_am*)(s + 8);
    }
    v4s vpC[4];
#pragma unroll
    for (int g = 0; g < 4; ++g) vpC[g] = *(const v4s_am*)(vrow0 + g * 16);

    // --- LN + Q projection per window: qf[wi] = Q^T fragment ---
    v4s qf[2];
#pragma unroll
    for (int wi = 0; wi < 2; ++wi) {
        int wc = wcp * 2 + wi;
        int qh = wr * 4 + (n15 >> 2), qw_ = wc * 4 + (n15 & 3);
        int qpix = b * 2304 + qh * 48 + qw_;
        float mu = MuRs[qpix * 2], rstd = MuRs[qpix * 2 + 1];
        v8s xln[4];
#pragma unroll
        for (int kc = 0; kc < 4; ++kc) {
            v8s x  = *(const v8s_am*)&Xt[(size_t)qpix * 128 + kc * 32 + quad * 8];
            v8s lw = *(const v8s_am*)&lnwb[kc * 32 + quad * 8];
            v8s lb = *(const v8s_am*)&lnbb[kc * 32 + quad * 8];
            v8s y;
#pragma unroll
            for (int j = 0; j < 8; ++j)
                y[j] = (short)f2b((b2f((u16)x[j]) - mu) * rstd * b2f((u16)lw[j]) + b2f((u16)lb[j]));
            xln[kc] = y;
        }
        int n0 = wave * 16;
        v4f qacc = zz4;
#pragma unroll
        for (int kc = 0; kc < 4; ++kc) {
            v8s aw = *(const v8s_am*)&qwb[((size_t)(n0 + n15)) * 128 + kc * 32 + quad * 8];
            qacc = MFMA_BF16(aw, xln[kc], qacc);
        }
        v4s q4;
#pragma unroll
        for (int r = 0; r < 4; ++r)
            q4[r] = (short)f2b((qacc[r] + qb[n0 + quad * 4 + r]) * QSCALE);
        qf[wi] = q4;
    }

    // --- local K/V projection per window (this wave's head only) ---
    v4s kfloc[2][4];
#pragma unroll
    for (int wi = 0; wi < 2; ++wi) {
        int wc = wcp * 2 + wi;
#pragma unroll
        for (int g = 0; g < 4; ++g) {
            int tl = g * 16 + n15;
            int fh = tl >> 3, fw = tl & 7;
            int hh = wr * 4 - 2 + fh, ww = wc * 4 - 2 + fw;
            bool valid = (hh >= 0 && hh < 48 && ww >= 0 && ww < 48);
            size_t arow = (size_t)(b * 2304 + hh * 48 + ww) * 128;
            v8s xb[4];
#pragma unroll
            for (int kc = 0; kc < 4; ++kc) {
                v8s v = zf8;
                if (valid) v = *(const v8s_am*)&Xt[arow + kc * 32 + quad * 8];
                xb[kc] = v;
            }
#pragma unroll
            for (int s = 0; s < 2; ++s) {    // s=0: K strip, s=1: V strip
                int sbase = s * 128 + wave * 16;
                v4f acc = zz4;
#pragma unroll
                for (int kc = 0; kc < 4; ++kc) {
                    v8s aw = *(const v8s_am*)&kvwb[((size_t)(sbase + n15)) * 128 + kc * 32 + quad * 8];
                    acc = MFMA_BF16(aw, xb[kc], acc);
                }
                if (s == 0) {
                    v4s k4;
#pragma unroll
                    for (int r = 0; r < 4; ++r)
                        k4[r] = (short)f2b(acc[r] + kvb[sbase + quad * 4 + r]);
                    kfloc[wi][g] = k4;
                } else {
#pragma unroll
                    for (int r = 0; r < 4; ++r)
                        VtW[wave][wi][quad * 4 + r][g * 16 + n15] =
                            f2b(acc[r] + kvb[sbase + quad * 4 + r]);
                }
            }
        }
    }

    // --- stage tile 0 into KP buf0 (vmcnt wait for kC only, per-wave) ---
    *(v8s_am*)&KPw[lane * 16]     = kC0;
    *(v8s_am*)&KPw[lane * 16 + 8] = kC1;

    // --- issue tile-1 K slice + V fragments ---
    v8s kN0, kN1;
    {
        const u16* s = kvcol + (size_t)(rbase_of(b, 1) + lane) * 128;
        kN0 = *(const v8s_am*)s; kN1 = *(const v8s_am*)(s + 8);
    }
    v4s vpN[4];
#pragma unroll
    for (int g = 0; g < 4; ++g) vpN[g] = *(const v4s_am*)(vrow0 + 64 + g * 16);

    v4f oacc[2] = {};
    float ls0 = 0.f, ls1 = 0.f;

    // --- local chunk (K frags in regs, V from wave-private LDS slice) ---
    asm volatile("s_waitcnt lgkmcnt(0)" ::: "memory");
#pragma unroll
    for (int wi = 0; wi < 2; ++wi) {
#pragma unroll
        for (int g = 0; g < 4; ++g) {
            v4f St = MFMA16(kfloc[wi][g], qf[wi], zz4);  // S^T[tok][q=n15]
            float p0 = EXP2(St[0]), p1 = EXP2(St[1]);
            float p2 = EXP2(St[2]), p3 = EXP2(St[3]);
            if (wi == 0) ls0 += (p0 + p1) + (p2 + p3);
            else         ls1 += (p0 + p1) + (p2 + p3);
            v4s pk = {(short)f2b(p0), (short)f2b(p1), (short)f2b(p2), (short)f2b(p3)};
            v4s vf = *(const v4s_am*)&VtW[wave][wi][n15][g * 16 + quad * 4];
            oacc[wi] = MFMA16(vf, pk, oacc[wi]);         // O^T[ch][q=n15]
        }
    }
    // All VtW reads done; barrier so later At-overlay writes can't race them.
    __syncthreads();

    // --- F-residual prefetch (cold HBM reads, ~40us ahead of use) ---
    float fres[2][4];
#pragma unroll
    for (int wi = 0; wi < 2; ++wi) {
        int wc = wcp * 2 + wi;
        int c = wave * 16 + n15;
#pragma unroll
        for (int r = 0; r < 4; ++r) {
            int pix = quad * 4 + r;
            int hh = wr * 4 + (pix >> 2), ww_ = wc * 4 + (pix & 3);
            fres[wi][r] = F[((size_t)(b * 128 + c)) * 2304 + hh * 48 + ww_];
        }
    }

    // --- pooled tiles 0..10: barrier-free, wave-private double buffer ---
#pragma unroll
    for (int tb = 0; tb < 11; ++tb) {
        // prefetch tile tb+2 (K slice + V frags)
        v8s kX0, kX1; v4s vpX[4];
        if (tb < 10) {
            int t2 = tb + 2;
            int row = (t2 == 11) ? (2304 + b * 144 + 128 + (lane & 15))
                                 : (rbase_of(b, t2) + lane);
            const u16* s = kvcol + (size_t)row * 128;
            kX0 = *(const v8s_am*)s; kX1 = *(const v8s_am*)(s + 8);
            if (t2 == 11) {
                vpX[0] = *(const v4s_am*)(vrow0 + 704);
                vpX[1] = vpX[0]; vpX[2] = vpX[0]; vpX[3] = vpX[0];
            } else {
#pragma unroll
                for (int g = 0; g < 4; ++g)
                    vpX[g] = *(const v4s_am*)(vrow0 + t2 * 64 + g * 16);
            }
        } else { kX0 = kN0; kX1 = kN1; vpX[0] = vpX[1] = vpX[2] = vpX[3] = vpN[0]; }
        // stage tile tb+1 into the other buffer (vmcnt waits kN only)
        {
            u16* kp1 = KPw + ((tb + 1) & 1) * 1024;
            *(v8s_am*)&kp1[lane * 16]     = kN0;
            *(v8s_am*)&kp1[lane * 16 + 8] = kN1;
        }
        // compute tile tb from KP[cur] with vpC
        {
            const u16* kp0 = KPw + (tb & 1) * 1024;
#pragma unroll
            for (int g = 0; g < 4; ++g) {
                v4s kf = *(const v4s_am*)&kp0[(g * 16 + n15) * 16 + quad * 4];
                v4f St0 = MFMA16(kf, qf[0], zz4);
                v4f St1 = MFMA16(kf, qf[1], zz4);
                float a0 = EXP2(St0[0]), a1 = EXP2(St0[1]), a2 = EXP2(St0[2]), a3 = EXP2(St0[3]);
                float b0 = EXP2(St1[0]), b1 = EXP2(St1[1]), b2 = EXP2(St1[2]), b3 = EXP2(St1[3]);
                ls0 += (a0 + a1) + (a2 + a3);
                ls1 += (b0 + b1) + (b2 + b3);
                v4s pk0 = {(short)f2b(a0), (short)f2b(a1), (short)f2b(a2), (short)f2b(a3)};
                v4s pk1 = {(short)f2b(b0), (short)f2b(b1), (short)f2b(b2), (short)f2b(b3)};
                oacc[0] = MFMA16(vpC[g], pk0, oacc[0]);
                oacc[1] = MFMA16(vpC[g], pk1, oacc[1]);
            }
        }
        // rotate rolling registers (unrolled loop -> SSA, no dynamic index)
#pragma unroll
        for (int g = 0; g < 4; ++g) vpC[g] = vpN[g];
        kN0 = kX0; kN1 = kX1;
#pragma unroll
        for (int g = 0; g < 4; ++g) vpN[g] = vpX[g];
    }
    // --- tile 11: 16 toks (glo 128..143), in KP buf1, V in vpC[0] ---
    {
        const u16* kp1 = KPw + 1024;
        v4s kf = *(const v4s_am*)&kp1[n15 * 16 + quad * 4];
        v4f St0 = MFMA16(kf, qf[0], zz4);
        v4f St1 = MFMA16(kf, qf[1], zz4);
        float a0 = EXP2(St0[0]), a1 = EXP2(St0[1]), a2 = EXP2(St0[2]), a3 = EXP2(St0[3]);
        float b0 = EXP2(St1[0]), b1 = EXP2(St1[1]), b2 = EXP2(St1[2]), b3 = EXP2(St1[3]);
        ls0 += (a0 + a1) + (a2 + a3);
        ls1 += (b0 + b1) + (b2 + b3);
        v4s pk0 = {(short)f2b(a0), (short)f2b(a1), (short)f2b(a2), (short)f2b(a3)};
        v4s pk1 = {(short)f2b(b0), (short)f2b(b1), (short)f2b(b2), (short)f2b(b3)};
        oacc[0] = MFMA16(vpC[0], pk0, oacc[0]);
        oacc[1] = MFMA16(vpC[0], pk1, oacc[1]);
    }

    // --- l reduce; write attended into At (overlay on VtW[0..1]; every
    //     wave passed the early barrier after its VtW reads) ---
#pragma unroll
    for (int wi = 0; wi < 2; ++wi) {
        float ls = wi == 0 ? ls0 : ls1;
        ls += __shfl_xor(ls, 16);
        ls += __shfl_xor(ls, 32);
        float inv = 1.f / ls;
        v4s a4 = {(short)f2b(oacc[wi][0] * inv), (short)f2b(oacc[wi][1] * inv),
                  (short)f2b(oacc[wi][2] * inv), (short)f2b(oacc[wi][3] * inv)};
        *(v4s_am*)&Atp[wi * 2176 + n15 * 136 + wave * 16 + quad * 4] = a4;
    }
    __syncthreads();    // barrier 2: At complete before out-proj reads

    // --- out projection (16 out-ch per wave) + bias + residual, NCHW ---
#pragma unroll
    for (int wi = 0; wi < 2; ++wi) {
        int wc = wcp * 2 + wi;
        int n0 = wave * 16;
        v4f oa = zz4;
#pragma unroll
        for (int kc = 0; kc < 4; ++kc) {
            v8s af = *(const v8s_am*)&Atp[wi * 2176 + n15 * 136 + kc * 32 + quad * 8];
            v8s bf = *(const v8s_am*)&owb[((size_t)(n0 + n15)) * 128 + kc * 32 + quad * 8];
            oa = MFMA_BF16(af, bf, oa);
        }
        int c = n0 + n15;
        float bv = ob[c];
#pragma unroll
        for (int r = 0; r < 4; ++r) {
            int pix = quad * 4 + r;
            int hh = wr * 4 + (pix >> 2), ww_ = wc * 4 + (pix & 3);
            size_t idx = ((size_t)(b * 128 + c)) * 2304 + hh * 48 + ww_;
            Out[idx] = oa[r] + bv + fres[wi][r];
        }
    }
}

// ---------------------------------------------------------------------------
extern "C" void kernel_launch(void* const* d_in, const int* in_sizes, int n_in,
                              void* d_out, int out_size, void* d_ws, size_t ws_size,
                              hipStream_t stream)
{
    const float* F   = (const float*)d_in[0];
    const float* lnw = (const float*)d_in[1];
    const float* lnb = (const float*)d_in[2];
    const float* qw  = (const float*)d_in[3];
    const float* qb  = (const float*)d_in[4];
    const float* kvw = (const float*)d_in[5];
    const float* kvb = (const float*)d_in[6];
    const float* ow  = (const float*)d_in[7];
    const float* ob  = (const float*)d_in[8];
    float* Out = (float*)d_out;

    u16* ws    = (u16*)d_ws;
    u16* Xt    = ws;                    // 9216*128  = 1,179,648 u16
    u16* Pml   = Xt + 9216 * 128;       // (unused; layout kept)
    u16* KVg   = Pml + 2880 * 128;      // 2880*128  =   368,640
    u16* VTg   = KVg + 2880 * 128;      // 4*128*720 =   368,640
    u16* Wb    = VTg + 4 * 128 * 720;   // 65,792 [qwb|kvwb|owb|lnwb|lnbb]
    float* MuRs = (float*)(Wb + 65792); // 9216*2 fp32
    // total: ~4.77 MiB

    k_prep_gemm<<<484, 256, 0, stream>>>(F, qw, kvw, ow, lnw, lnb, kvb,
                                         Xt, Wb, MuRs, KVg, VTg);
    k_attn_fused<<<288, 512, 0, stream>>>(F, Xt, MuRs, KVg, VTg, Wb,
                                          qb, kvb, ob, Out);
}

// Round 8
// 191.897 us; speedup vs baseline: 1.0996x; 1.0996x over previous
//
#include <hip/hip_runtime.h>

// FocalSelfAttention on MI355X. fp32 I/O, bf16 MFMA compute, fp32 accum.
// B=4, C=128, H=W=48, WS=4 -> 144 windows/batch, 16 q/window, NH=8, hd=16,
// Nkv = 64 local + 720 pooled.
//
// v16:
//  * prep/gemm: reverted to v12's split (best measured rest: 78.7 us).
//    Only change: K output now HEAD-MAJOR KVh[8][2880][16] (same bytes) so
//    an attn wave's per-tile K slice is one contiguous 2KB read.
//  * attn: v14's 2-window 8-wave shape, but the pooled loop is BARRIER-FREE:
//    wave-private SINGLE-buffer KP[wave][64][16] (per-wave DS ops are
//    in-order: read tile t, then overwrite with t+1 -- no barrier, no dbuf).
//    Prefetch state is flat 2-deep (kN + vpN/vpC, 24 VGPR), no if/else
//    merges (v15's 3-deep rolling regs spilled -> 187MB scratch writes).
//    Barriers in kernel: 2 (At overlay + before out-proj). LDS 50 KB.

typedef unsigned short u16;
typedef short v8s __attribute__((ext_vector_type(8)));
typedef v8s __attribute__((may_alias)) v8s_am;
typedef short v4s __attribute__((ext_vector_type(4)));
typedef v4s __attribute__((may_alias)) v4s_am;
typedef float v4f __attribute__((ext_vector_type(4)));

#define MFMA_BF16(a, b, c) __builtin_amdgcn_mfma_f32_16x16x32_bf16(a, b, c, 0, 0, 0)

#if __has_builtin(__builtin_amdgcn_mfma_f32_16x16x16bf16_1k)
#define MFMA16(a, b, c) __builtin_amdgcn_mfma_f32_16x16x16bf16_1k(a, b, c, 0, 0, 0)
#else
static __device__ __forceinline__ v4f mfma16_fb(v4s a, v4s b, v4f c) {
    v8s a8 = {a[0], a[1], a[2], a[3], 0, 0, 0, 0};
    v8s b8 = {b[0], b[1], b[2], b[3], 0, 0, 0, 0};
    return MFMA_BF16(a8, b8, c);
}
#define MFMA16(a, b, c) mfma16_fb(a, b, c)
#endif

#if __has_builtin(__builtin_amdgcn_exp2f)
#define EXP2(x) __builtin_amdgcn_exp2f(x)
#else
#define EXP2(x) exp2f(x)
#endif

__device__ __forceinline__ float b2f(u16 u) {
    union { unsigned int i; float f; } x;
    x.i = ((unsigned int)u) << 16;
    return x.f;
}
__device__ __forceinline__ u16 f2b(float f) {
    union { float f; unsigned int i; } x;
    x.f = f;
    unsigned int u = x.i;
    return (u16)((u + 0x7fffu + ((u >> 16) & 1u)) >> 16);
}

// ---------------------------------------------------------------------------
// Kernel 1: blocks 0..287 transpose F->Xt + LN stats; 288..303 weights;
// 304..483 pooled tokens -> Pml. (v12 structure, best measured.)
__global__ __launch_bounds__(256) void k_prep(
    const float* __restrict__ F,
    const float* __restrict__ qw, const float* __restrict__ kvw,
    const float* __restrict__ ow,
    const float* __restrict__ lnw, const float* __restrict__ lnb,
    u16* __restrict__ Xt, u16* __restrict__ Wb, float* __restrict__ MuRs,
    u16* __restrict__ Pml)
{
    int blk = blockIdx.x;
    int t = threadIdx.x;
    if (blk >= 304) {   // ---- pool part: 180 blocks ----
        int gid = (blk - 304) * 256 + t;
        int row = gid >> 4;
        int seg = gid & 15;
        v8s outv;
        if (row < 2304) {        // mid: avg 2x2
            int b = row / 576, r = row % 576;
            int i = r / 24, j = r % 24;
#pragma unroll
            for (int jc = 0; jc < 8; ++jc) {
                int c = seg * 8 + jc;
                const float* src = F + ((size_t)(b * 128 + c)) * 2304 + (2 * i) * 48 + 2 * j;
                float2 a = *(const float2*)src;
                float2 d = *(const float2*)(src + 48);
                outv[jc] = (short)f2b((a.x + a.y + d.x + d.y) * 0.25f);
            }
        } else {                 // glo: avg 4x4
            int r2 = row - 2304;
            int b = r2 / 144, r = r2 % 144;
            int i = r / 12, j = r % 12;
#pragma unroll
            for (int jc = 0; jc < 8; ++jc) {
                int c = seg * 8 + jc;
                const float* src = F + ((size_t)(b * 128 + c)) * 2304 + (4 * i) * 48 + 4 * j;
                float s = 0.f;
#pragma unroll
                for (int di = 0; di < 4; ++di) {
                    float4 v = *(const float4*)(src + di * 48);
                    s += (v.x + v.y) + (v.z + v.w);
                }
                outv[jc] = (short)f2b(s * 0.0625f);
            }
        }
        *(v8s_am*)&Pml[((size_t)row) * 128 + seg * 8] = outv;
        return;
    }
    if (blk >= 288) {   // ---- weight conversion: 16 blocks ----
        int base = (blk - 288) * 4096 + t * 16;
#pragma unroll
        for (int i = 0; i < 4; ++i) {
            int idx = base + i * 4;
            const float* src; int off;
            if (idx < 16384)      { src = qw;  off = idx; }
            else if (idx < 49152) { src = kvw; off = idx - 16384; }
            else                  { src = ow;  off = idx - 49152; }
            float4 v = *(const float4*)(src + off);
            unsigned long long packed =
                (unsigned long long)f2b(v.x) |
                ((unsigned long long)f2b(v.y) << 16) |
                ((unsigned long long)f2b(v.z) << 32) |
                ((unsigned long long)f2b(v.w) << 48);
            *(unsigned long long*)(Wb + idx) = packed;
        }
        if (blk == 288) {
            Wb[65536 + t] = f2b(t < 128 ? lnw[t] : lnb[t - 128]);
        }
        return;
    }
    // ---- transpose + LN stats: 288 blocks ----
    __shared__ u16 X[128][34];
    int b = blk / 72;
    int p0 = (blk % 72) * 32;
#pragma unroll 4
    for (int i = 0; i < 16; ++i) {
        int c = i * 8 + (t >> 5);
        int pix = t & 31;
        X[c][pix] = f2b(F[((size_t)(b * 128 + c)) * 2304 + p0 + pix]);
    }
    __syncthreads();
    int pix = t >> 3;
    int c0 = (t & 7) * 16;
    size_t row = (size_t)(b * 2304 + p0 + pix) * 128;
    float s = 0.f, s2 = 0.f;
#pragma unroll
    for (int sg = 0; sg < 2; ++sg) {
        v8s raw;
#pragma unroll
        for (int j = 0; j < 8; ++j) {
            u16 u = X[c0 + sg * 8 + j][pix];
            raw[j] = (short)u;
            float v = b2f(u);
            s += v; s2 += v * v;
        }
        *(v8s_am*)&Xt[row + c0 + sg * 8] = raw;
    }
    s += __shfl_xor(s, 1);  s2 += __shfl_xor(s2, 1);
    s += __shfl_xor(s, 2);  s2 += __shfl_xor(s2, 2);
    s += __shfl_xor(s, 4);  s2 += __shfl_xor(s2, 4);
    if ((t & 7) == 0) {
        float mean = s * (1.f / 128.f);
        float var = s2 * (1.f / 128.f) - mean * mean;
        float rstd = rsqrtf(var + 1e-5f);
        MuRs[(b * 2304 + p0 + pix) * 2]     = mean;
        MuRs[(b * 2304 + p0 + pix) * 2 + 1] = rstd;
    }
}

// ---------------------------------------------------------------------------
// Kernel 2: mid/glo K/V projection from Pml (v12 structure).
// K -> HEAD-MAJOR KVh[8][2880][16]; V -> VTg[b][128 ch][720 tok].
__global__ __launch_bounds__(256) void k_gemm_kv(
    const u16* __restrict__ Pml,
    const u16* __restrict__ W,
    const float* __restrict__ bias,
    u16* __restrict__ KVh,
    u16* __restrict__ VTg)
{
    __shared__ u16 Al[64][136];
    __shared__ u16 Wl[64][136];
    int tm = blockIdx.x * 64, tn = blockIdx.y * 64;
    int t = threadIdx.x;
    {
        int seg = t & 15, r0 = t >> 4;
#pragma unroll
        for (int i = 0; i < 4; ++i) {
            int r = r0 + 16 * i;
            *(v8s_am*)&Al[r][seg * 8] = *(const v8s_am*)&Pml[((size_t)(tm + r)) * 128 + seg * 8];
            *(v8s_am*)&Wl[r][seg * 8] = *(const v8s_am*)&W[((size_t)(tn + r)) * 128 + seg * 8];
        }
    }
    __syncthreads();
    int lane = t & 63, wave = t >> 6;
    int n15 = lane & 15, quad = lane >> 4;
    int wm = (wave & 1) * 32, wn = (wave >> 1) * 32;
    v4f acc[2][2] = {};
#pragma unroll
    for (int kc = 0; kc < 4; ++kc) {
        v8s a[2], bb[2];
#pragma unroll
        for (int im = 0; im < 2; ++im)
            a[im] = *(const v8s_am*)&Al[wm + im * 16 + n15][kc * 32 + quad * 8];
#pragma unroll
        for (int in = 0; in < 2; ++in)
            bb[in] = *(const v8s_am*)&Wl[wn + in * 16 + n15][kc * 32 + quad * 8];
#pragma unroll
        for (int im = 0; im < 2; ++im)
#pragma unroll
            for (int in = 0; in < 2; ++in)
                acc[im][in] = MFMA_BF16(a[im], bb[in], acc[im][in]);
    }
#pragma unroll
    for (int in = 0; in < 2; ++in) {
        int n = tn + wn + in * 16 + n15;
        float bv = bias[n];
#pragma unroll
        for (int im = 0; im < 2; ++im) {
            int mbase = tm + wm + im * 16 + quad * 4;
#pragma unroll
            for (int r = 0; r < 4; ++r) {
                int m = mbase + r;
                u16 h = f2b(acc[im][in][r] + bv);
                if (n < 128) {
                    KVh[((size_t)(n >> 4) * 2880 + m) * 16 + (n & 15)] = h;
                } else {
                    int ch = n - 128, bb2, tok;
                    if (m < 2304) { bb2 = m / 576; tok = m % 576; }
                    else { int r2 = m - 2304; bb2 = r2 / 144; tok = 576 + r2 % 144; }
                    VTg[((size_t)(bb2 * 128 + ch)) * 720 + tok] = h;
                }
            }
        }
    }
}

// ---------------------------------------------------------------------------
// Kernel 3: fused attention, 2 windows/block, 288 blocks x 512 thr (8 waves,
// wave = head). Barrier-free pooled loop: wave-private single-buffer KP
// (per-wave DS ops in-order), flat 2-deep prefetch. 2 barriers total.
__global__ __launch_bounds__(512, 4) void k_attn_fused(
    const float* __restrict__ F,
    const u16* __restrict__ Xt,
    const float* __restrict__ MuRs,
    const u16* __restrict__ KVh,     // [8][2880][16] head-major
    const u16* __restrict__ VTg,
    const u16* __restrict__ Wb,      // [qwb|kvwb|owb|lnwb|lnbb]
    const float* __restrict__ qb,
    const float* __restrict__ kvb,
    const float* __restrict__ ob,
    float* __restrict__ Out)
{
    __shared__ u16 KP[8][64][16];       // wave-private K tile (16 KB)
    __shared__ u16 VtW[8][2][16][68];   // per-wave/window local V^T (34.8 KB)

    const u16* qwb  = Wb;
    const u16* kvwb = Wb + 16384;
    const u16* owb  = Wb + 49152;
    const u16* lnwb = Wb + 65536;
    const u16* lnbb = Wb + 65664;
    u16* Atp = &VtW[0][0][0][0];        // overlay [2][16][136] = 4352 u16

    // Bijective XCD swizzle: 288 = 8 xcd x 36. xcd -> one batch-half.
    int blk = blockIdx.x;
    int xcd = blk & 7, jj = blk >> 3;   // jj 0..35
    int b = xcd >> 1;
    int wr = (xcd & 1) * 6 + jj / 6;
    int wcp = jj % 6;                   // windows wc = 2*wcp + {0,1}

    int t = threadIdx.x;
    int lane = t & 63, wave = t >> 6, n15 = lane & 15, quad = lane >> 4;
    v8s zf8 = {};
    v4f zz4 = {0.f, 0.f, 0.f, 0.f};
    const float QSCALE = 0.25f * 1.44269504f;

    u16* KPw = &KP[wave][0][0];
    const u16* kwave = KVh + (size_t)wave * 46080;   // this head's K rows
    const u16* vrow0 = VTg + (size_t)b * 92160
                     + (size_t)(wave * 16 + n15) * 720 + quad * 4;

    // --- issue tile-0 K slice (contiguous 2KB/wave) + V fragments first ---
    v8s kN0, kN1;
    {
        const u16* s = kwave + (size_t)(b * 576 + lane) * 16;
        kN0 = *(const v8s_am*)s; kN1 = *(const v8s_am*)(s + 8);
    }
    v4s vpC[4], vpN[4];
#pragma unroll
    for (int g = 0; g < 4; ++g) vpC[g] = *(const v4s_am*)(vrow0 + g * 16);

    // --- LN + Q projection per window ---
    v4s qf[2];
#pragma unroll
    for (int wi = 0; wi < 2; ++wi) {
        int wc = wcp * 2 + wi;
        int qh = wr * 4 + (n15 >> 2), qw_ = wc * 4 + (n15 & 3);
        int qpix = b * 2304 + qh * 48 + qw_;
        float mu = MuRs[qpix * 2], rstd = MuRs[qpix * 2 + 1];
        v8s xln[4];
#pragma unroll
        for (int kc = 0; kc < 4; ++kc) {
            v8s x  = *(const v8s_am*)&Xt[(size_t)qpix * 128 + kc * 32 + quad * 8];
            v8s lw = *(const v8s_am*)&lnwb[kc * 32 + quad * 8];
            v8s lb = *(const v8s_am*)&lnbb[kc * 32 + quad * 8];
            v8s y;
#pragma unroll
            for (int j = 0; j < 8; ++j)
                y[j] = (short)f2b((b2f((u16)x[j]) - mu) * rstd * b2f((u16)lw[j]) + b2f((u16)lb[j]));
            xln[kc] = y;
        }
        int n0 = wave * 16;
        v4f qacc = zz4;
#pragma unroll
        for (int kc = 0; kc < 4; ++kc) {
            v8s aw = *(const v8s_am*)&qwb[((size_t)(n0 + n15)) * 128 + kc * 32 + quad * 8];
            qacc = MFMA_BF16(aw, xln[kc], qacc);
        }
        v4s q4;
#pragma unroll
        for (int r = 0; r < 4; ++r)
            q4[r] = (short)f2b((qacc[r] + qb[n0 + quad * 4 + r]) * QSCALE);
        qf[wi] = q4;
    }

    // --- local K/V projection per window (this wave's head only) ---
    v4s kfloc[2][4];
#pragma unroll
    for (int wi = 0; wi < 2; ++wi) {
        int wc = wcp * 2 + wi;
#pragma unroll
        for (int g = 0; g < 4; ++g) {
            int tl = g * 16 + n15;
            int fh = tl >> 3, fw = tl & 7;
            int hh = wr * 4 - 2 + fh, ww = wc * 4 - 2 + fw;
            bool valid = (hh >= 0 && hh < 48 && ww >= 0 && ww < 48);
            size_t arow = (size_t)(b * 2304 + hh * 48 + ww) * 128;
            v8s xb[4];
#pragma unroll
            for (int kc = 0; kc < 4; ++kc) {
                v8s v = zf8;
                if (valid) v = *(const v8s_am*)&Xt[arow + kc * 32 + quad * 8];
                xb[kc] = v;
            }
#pragma unroll
            for (int s = 0; s < 2; ++s) {    // s=0: K strip, s=1: V strip
                int sbase = s * 128 + wave * 16;
                v4f acc = zz4;
#pragma unroll
                for (int kc = 0; kc < 4; ++kc) {
                    v8s aw = *(const v8s_am*)&kvwb[((size_t)(sbase + n15)) * 128 + kc * 32 + quad * 8];
                    acc = MFMA_BF16(aw, xb[kc], acc);
                }
                if (s == 0) {
                    v4s k4;
#pragma unroll
                    for (int r = 0; r < 4; ++r)
                        k4[r] = (short)f2b(acc[r] + kvb[sbase + quad * 4 + r]);
                    kfloc[wi][g] = k4;
                } else {
#pragma unroll
                    for (int r = 0; r < 4; ++r)
                        VtW[wave][wi][quad * 4 + r][g * 16 + n15] =
                            f2b(acc[r] + kvb[sbase + quad * 4 + r]);
                }
            }
        }
    }

    v4f oacc[2] = {};
    float ls0 = 0.f, ls1 = 0.f;

    // --- local chunk (K frags in regs, V from wave-private LDS slice) ---
    asm volatile("s_waitcnt lgkmcnt(0)" ::: "memory");
#pragma unroll
    for (int wi = 0; wi < 2; ++wi) {
#pragma unroll
        for (int g = 0; g < 4; ++g) {
            v4f St = MFMA16(kfloc[wi][g], qf[wi], zz4);  // S^T[tok][q=n15]
            float p0 = EXP2(St[0]), p1 = EXP2(St[1]);
            float p2 = EXP2(St[2]), p3 = EXP2(St[3]);
            if (wi == 0) ls0 += (p0 + p1) + (p2 + p3);
            else         ls1 += (p0 + p1) + (p2 + p3);
            v4s pk = {(short)f2b(p0), (short)f2b(p1), (short)f2b(p2), (short)f2b(p3)};
            v4s vf = *(const v4s_am*)&VtW[wave][wi][n15][g * 16 + quad * 4];
            oacc[wi] = MFMA16(vf, pk, oacc[wi]);         // O^T[ch][q=n15]
        }
    }
    // All VtW reads done -> later At-overlay writes can't race them.
    __syncthreads();    // barrier 1 (also drains tile-0 loads)

    // --- F-residual prefetch (cold HBM, used only in epilogue) ---
    float fres[2][4];
#pragma unroll
    for (int wi = 0; wi < 2; ++wi) {
        int wc = wcp * 2 + wi;
        int c = wave * 16 + n15;
#pragma unroll
        for (int r = 0; r < 4; ++r) {
            int pix = quad * 4 + r;
            int hh = wr * 4 + (pix >> 2), ww_ = wc * 4 + (pix & 3);
            fres[wi][r] = F[((size_t)(b * 128 + c)) * 2304 + hh * 48 + ww_];
        }
    }

    // --- stage tile 0 (kN complete: drained by barrier 1) ---
    *(v8s_am*)&KPw[lane * 16]     = kN0;
    *(v8s_am*)&KPw[lane * 16 + 8] = kN1;
    // issue tile-1 K + V
    {
        const u16* s = kwave + (size_t)(b * 576 + 64 + lane) * 16;
        kN0 = *(const v8s_am*)s; kN1 = *(const v8s_am*)(s + 8);
    }
#pragma unroll
    for (int g = 0; g < 4; ++g) vpN[g] = *(const v4s_am*)(vrow0 + 64 + g * 16);

    // --- pooled tiles 0..11: barrier-free, wave-private single buffer ---
#pragma unroll
    for (int tb = 0; tb <= 11; ++tb) {
        // read this tile's K fragments (tile tb, written last round)
        v4s kf[4];
#pragma unroll
        for (int g = 0; g < 4; ++g)
            kf[g] = *(const v4s_am*)&KPw[(g * 16 + n15) * 16 + quad * 4];
        // overwrite KP with tile tb+1 (same-wave DS ops are in-order)
        if (tb < 11) {
            *(v8s_am*)&KPw[lane * 16]     = kN0;
            *(v8s_am*)&KPw[lane * 16 + 8] = kN1;
            if (tb < 10) {   // issue K(tb+2)
                int t2 = tb + 2;
                int row = (t2 < 9) ? (b * 576 + t2 * 64 + lane)
                                   : (2304 + b * 144 + (t2 - 9) * 64 + lane);
                if (t2 == 11) row = min(2304 + b * 144 + 128 + lane, 2879);
                const u16* s = kwave + (size_t)row * 16;
                kN0 = *(const v8s_am*)s; kN1 = *(const v8s_am*)(s + 8);
            }
        }
        // compute tile tb (tb==11: only 16 tokens -> g=0)
#pragma unroll
        for (int g = 0; g < ((tb == 11) ? 1 : 4); ++g) {
            v4f St0 = MFMA16(kf[g], qf[0], zz4);
            v4f St1 = MFMA16(kf[g], qf[1], zz4);
            float a0 = EXP2(St0[0]), a1 = EXP2(St0[1]), a2 = EXP2(St0[2]), a3 = EXP2(St0[3]);
            float b0 = EXP2(St1[0]), b1 = EXP2(St1[1]), b2 = EXP2(St1[2]), b3 = EXP2(St1[3]);
            ls0 += (a0 + a1) + (a2 + a3);
            ls1 += (b0 + b1) + (b2 + b3);
            v4s pk0 = {(short)f2b(a0), (short)f2b(a1), (short)f2b(a2), (short)f2b(a3)};
            v4s pk1 = {(short)f2b(b0), (short)f2b(b1), (short)f2b(b2), (short)f2b(b3)};
            oacc[0] = MFMA16(vpC[g], pk0, oacc[0]);
            oacc[1] = MFMA16(vpC[g], pk1, oacc[1]);
        }
        // rotate V regs and issue V(tb+2)
        if (tb < 11) {
#pragma unroll
            for (int g = 0; g < 4; ++g) vpC[g] = vpN[g];
            if (tb < 10) {
                int t2 = tb + 2;
#pragma unroll
                for (int g = 0; g < 4; ++g) {
                    int off = (t2 == 11) ? 704 : (t2 * 64 + g * 16);
                    vpN[g] = *(const v4s_am*)(vrow0 + off);
                }
            }
        }
    }

    // --- l reduce; write attended into At (overlay on VtW[0..1]) ---
#pragma unroll
    for (int wi = 0; wi < 2; ++wi) {
        float ls = wi == 0 ? ls0 : ls1;
        ls += __shfl_xor(ls, 16);
        ls += __shfl_xor(ls, 32);
        float inv = 1.f / ls;
        v4s a4 = {(short)f2b(oacc[wi][0] * inv), (short)f2b(oacc[wi][1] * inv),
                  (short)f2b(oacc[wi][2] * inv), (short)f2b(oacc[wi][3] * inv)};
        *(v4s_am*)&Atp[wi * 2176 + n15 * 136 + wave * 16 + quad * 4] = a4;
    }
    __syncthreads();    // barrier 2: At complete before out-proj reads

    // --- out projection (16 out-ch per wave) + bias + residual, NCHW ---
#pragma unroll
    for (int wi = 0; wi < 2; ++wi) {
        int wc = wcp * 2 + wi;
        int n0 = wave * 16;
        v4f oa = zz4;
#pragma unroll
        for (int kc = 0; kc < 4; ++kc) {
            v8s af = *(const v8s_am*)&Atp[wi * 2176 + n15 * 136 + kc * 32 + quad * 8];
            v8s bf = *(const v8s_am*)&owb[((size_t)(n0 + n15)) * 128 + kc * 32 + quad * 8];
            oa = MFMA_BF16(af, bf, oa);
        }
        int c = n0 + n15;
        float bv = ob[c];
#pragma unroll
        for (int r = 0; r < 4; ++r) {
            int pix = quad * 4 + r;
            int hh = wr * 4 + (pix >> 2), ww_ = wc * 4 + (pix & 3);
            size_t idx = ((size_t)(b * 128 + c)) * 2304 + hh * 48 + ww_;
            Out[idx] = oa[r] + bv + fres[wi][r];
        }
    }
}

// ---------------------------------------------------------------------------
extern "C" void kernel_launch(void* const* d_in, const int* in_sizes, int n_in,
                              void* d_out, int out_size, void* d_ws, size_t ws_size,
                              hipStream_t stream)
{
    const float* F   = (const float*)d_in[0];
    const float* lnw = (const float*)d_in[1];
    const float* lnb = (const float*)d_in[2];
    const float* qw  = (const float*)d_in[3];
    const float* qb  = (const float*)d_in[4];
    const float* kvw = (const float*)d_in[5];
    const float* kvb = (const float*)d_in[6];
    const float* ow  = (const float*)d_in[7];
    const float* ob  = (const float*)d_in[8];
    float* Out = (float*)d_out;

    u16* ws    = (u16*)d_ws;
    u16* Xt    = ws;                    // 9216*128  = 1,179,648 u16
    u16* Pml   = Xt + 9216 * 128;       // 2880*128  =   368,640
    u16* KVh   = Pml + 2880 * 128;      // 8*2880*16 =   368,640 (head-major)
    u16* VTg   = KVh + 8 * 2880 * 16;   // 4*128*720 =   368,640
    u16* Wb    = VTg + 4 * 128 * 720;   // 65,792 [qwb|kvwb|owb|lnwb|lnbb]
    float* MuRs = (float*)(Wb + 65792); // 9216*2 fp32
    // total: ~4.77 MiB
    u16* kvwb = Wb + 16384;

    k_prep<<<484, 256, 0, stream>>>(F, qw, kvw, ow, lnw, lnb, Xt, Wb, MuRs, Pml);
    k_gemm_kv<<<dim3(45, 4), 256, 0, stream>>>(Pml, kvwb, kvb, KVh, VTg);
    k_attn_fused<<<288, 512, 0, stream>>>(F, Xt, MuRs, KVh, VTg, Wb,
                                          qb, kvb, ob, Out);
}

// Round 9
// 188.916 us; speedup vs baseline: 1.1169x; 1.0158x over previous
//
#include <hip/hip_runtime.h>

// FocalSelfAttention on MI355X. fp32 I/O, bf16 MFMA compute, fp32 accum.
// B=4, C=128, H=W=48, WS=4 -> 144 windows/batch, 16 q/window, NH=8, hd=16,
// Nkv = 64 local + 720 pooled.
//
// v17 = v16 with ONE change: __launch_bounds__(512, 2) on k_attn_fused.
// Diagnosis: every spilling version (v11/v15/v16) reports VGPR_Count == 64
// exactly -- the toolchain honors the 2nd launch_bounds arg as BLOCKS/CU
// (CUDA semantics): (512,4) -> 32 waves/CU -> 8 waves/SIMD -> 512/8 = 64
// VGPR cap. v16's ~90-reg demand spilled to scratch (208 MB writes).
// (512,2) -> 16 waves/CU -> 4 waves/SIMD -> 128 VGPR cap; occupancy stays
// 2 blocks/CU (LDS 50 KB). This finally gives the barrier-free main loop
// (wave-private single-buffer KP staging, per-wave in-order DS, 2 barriers
// total) an honest test.

typedef unsigned short u16;
typedef short v8s __attribute__((ext_vector_type(8)));
typedef v8s __attribute__((may_alias)) v8s_am;
typedef short v4s __attribute__((ext_vector_type(4)));
typedef v4s __attribute__((may_alias)) v4s_am;
typedef float v4f __attribute__((ext_vector_type(4)));

#define MFMA_BF16(a, b, c) __builtin_amdgcn_mfma_f32_16x16x32_bf16(a, b, c, 0, 0, 0)

#if __has_builtin(__builtin_amdgcn_mfma_f32_16x16x16bf16_1k)
#define MFMA16(a, b, c) __builtin_amdgcn_mfma_f32_16x16x16bf16_1k(a, b, c, 0, 0, 0)
#else
static __device__ __forceinline__ v4f mfma16_fb(v4s a, v4s b, v4f c) {
    v8s a8 = {a[0], a[1], a[2], a[3], 0, 0, 0, 0};
    v8s b8 = {b[0], b[1], b[2], b[3], 0, 0, 0, 0};
    return MFMA_BF16(a8, b8, c);
}
#define MFMA16(a, b, c) mfma16_fb(a, b, c)
#endif

#if __has_builtin(__builtin_amdgcn_exp2f)
#define EXP2(x) __builtin_amdgcn_exp2f(x)
#else
#define EXP2(x) exp2f(x)
#endif

__device__ __forceinline__ float b2f(u16 u) {
    union { unsigned int i; float f; } x;
    x.i = ((unsigned int)u) << 16;
    return x.f;
}
__device__ __forceinline__ u16 f2b(float f) {
    union { float f; unsigned int i; } x;
    x.f = f;
    unsigned int u = x.i;
    return (u16)((u + 0x7fffu + ((u >> 16) & 1u)) >> 16);
}

// ---------------------------------------------------------------------------
// Kernel 1: blocks 0..287 transpose F->Xt + LN stats; 288..303 weights;
// 304..483 pooled tokens -> Pml. (v12 structure, best measured.)
__global__ __launch_bounds__(256) void k_prep(
    const float* __restrict__ F,
    const float* __restrict__ qw, const float* __restrict__ kvw,
    const float* __restrict__ ow,
    const float* __restrict__ lnw, const float* __restrict__ lnb,
    u16* __restrict__ Xt, u16* __restrict__ Wb, float* __restrict__ MuRs,
    u16* __restrict__ Pml)
{
    int blk = blockIdx.x;
    int t = threadIdx.x;
    if (blk >= 304) {   // ---- pool part: 180 blocks ----
        int gid = (blk - 304) * 256 + t;
        int row = gid >> 4;
        int seg = gid & 15;
        v8s outv;
        if (row < 2304) {        // mid: avg 2x2
            int b = row / 576, r = row % 576;
            int i = r / 24, j = r % 24;
#pragma unroll
            for (int jc = 0; jc < 8; ++jc) {
                int c = seg * 8 + jc;
                const float* src = F + ((size_t)(b * 128 + c)) * 2304 + (2 * i) * 48 + 2 * j;
                float2 a = *(const float2*)src;
                float2 d = *(const float2*)(src + 48);
                outv[jc] = (short)f2b((a.x + a.y + d.x + d.y) * 0.25f);
            }
        } else {                 // glo: avg 4x4
            int r2 = row - 2304;
            int b = r2 / 144, r = r2 % 144;
            int i = r / 12, j = r % 12;
#pragma unroll
            for (int jc = 0; jc < 8; ++jc) {
                int c = seg * 8 + jc;
                const float* src = F + ((size_t)(b * 128 + c)) * 2304 + (4 * i) * 48 + 4 * j;
                float s = 0.f;
#pragma unroll
                for (int di = 0; di < 4; ++di) {
                    float4 v = *(const float4*)(src + di * 48);
                    s += (v.x + v.y) + (v.z + v.w);
                }
                outv[jc] = (short)f2b(s * 0.0625f);
            }
        }
        *(v8s_am*)&Pml[((size_t)row) * 128 + seg * 8] = outv;
        return;
    }
    if (blk >= 288) {   // ---- weight conversion: 16 blocks ----
        int base = (blk - 288) * 4096 + t * 16;
#pragma unroll
        for (int i = 0; i < 4; ++i) {
            int idx = base + i * 4;
            const float* src; int off;
            if (idx < 16384)      { src = qw;  off = idx; }
            else if (idx < 49152) { src = kvw; off = idx - 16384; }
            else                  { src = ow;  off = idx - 49152; }
            float4 v = *(const float4*)(src + off);
            unsigned long long packed =
                (unsigned long long)f2b(v.x) |
                ((unsigned long long)f2b(v.y) << 16) |
                ((unsigned long long)f2b(v.z) << 32) |
                ((unsigned long long)f2b(v.w) << 48);
            *(unsigned long long*)(Wb + idx) = packed;
        }
        if (blk == 288) {
            Wb[65536 + t] = f2b(t < 128 ? lnw[t] : lnb[t - 128]);
        }
        return;
    }
    // ---- transpose + LN stats: 288 blocks ----
    __shared__ u16 X[128][34];
    int b = blk / 72;
    int p0 = (blk % 72) * 32;
#pragma unroll 4
    for (int i = 0; i < 16; ++i) {
        int c = i * 8 + (t >> 5);
        int pix = t & 31;
        X[c][pix] = f2b(F[((size_t)(b * 128 + c)) * 2304 + p0 + pix]);
    }
    __syncthreads();
    int pix = t >> 3;
    int c0 = (t & 7) * 16;
    size_t row = (size_t)(b * 2304 + p0 + pix) * 128;
    float s = 0.f, s2 = 0.f;
#pragma unroll
    for (int sg = 0; sg < 2; ++sg) {
        v8s raw;
#pragma unroll
        for (int j = 0; j < 8; ++j) {
            u16 u = X[c0 + sg * 8 + j][pix];
            raw[j] = (short)u;
            float v = b2f(u);
            s += v; s2 += v * v;
        }
        *(v8s_am*)&Xt[row + c0 + sg * 8] = raw;
    }
    s += __shfl_xor(s, 1);  s2 += __shfl_xor(s2, 1);
    s += __shfl_xor(s, 2);  s2 += __shfl_xor(s2, 2);
    s += __shfl_xor(s, 4);  s2 += __shfl_xor(s2, 4);
    if ((t & 7) == 0) {
        float mean = s * (1.f / 128.f);
        float var = s2 * (1.f / 128.f) - mean * mean;
        float rstd = rsqrtf(var + 1e-5f);
        MuRs[(b * 2304 + p0 + pix) * 2]     = mean;
        MuRs[(b * 2304 + p0 + pix) * 2 + 1] = rstd;
    }
}

// ---------------------------------------------------------------------------
// Kernel 2: mid/glo K/V projection from Pml (v12 structure).
// K -> HEAD-MAJOR KVh[8][2880][16]; V -> VTg[b][128 ch][720 tok].
__global__ __launch_bounds__(256) void k_gemm_kv(
    const u16* __restrict__ Pml,
    const u16* __restrict__ W,
    const float* __restrict__ bias,
    u16* __restrict__ KVh,
    u16* __restrict__ VTg)
{
    __shared__ u16 Al[64][136];
    __shared__ u16 Wl[64][136];
    int tm = blockIdx.x * 64, tn = blockIdx.y * 64;
    int t = threadIdx.x;
    {
        int seg = t & 15, r0 = t >> 4;
#pragma unroll
        for (int i = 0; i < 4; ++i) {
            int r = r0 + 16 * i;
            *(v8s_am*)&Al[r][seg * 8] = *(const v8s_am*)&Pml[((size_t)(tm + r)) * 128 + seg * 8];
            *(v8s_am*)&Wl[r][seg * 8] = *(const v8s_am*)&W[((size_t)(tn + r)) * 128 + seg * 8];
        }
    }
    __syncthreads();
    int lane = t & 63, wave = t >> 6;
    int n15 = lane & 15, quad = lane >> 4;
    int wm = (wave & 1) * 32, wn = (wave >> 1) * 32;
    v4f acc[2][2] = {};
#pragma unroll
    for (int kc = 0; kc < 4; ++kc) {
        v8s a[2], bb[2];
#pragma unroll
        for (int im = 0; im < 2; ++im)
            a[im] = *(const v8s_am*)&Al[wm + im * 16 + n15][kc * 32 + quad * 8];
#pragma unroll
        for (int in = 0; in < 2; ++in)
            bb[in] = *(const v8s_am*)&Wl[wn + in * 16 + n15][kc * 32 + quad * 8];
#pragma unroll
        for (int im = 0; im < 2; ++im)
#pragma unroll
            for (int in = 0; in < 2; ++in)
                acc[im][in] = MFMA_BF16(a[im], bb[in], acc[im][in]);
    }
#pragma unroll
    for (int in = 0; in < 2; ++in) {
        int n = tn + wn + in * 16 + n15;
        float bv = bias[n];
#pragma unroll
        for (int im = 0; im < 2; ++im) {
            int mbase = tm + wm + im * 16 + quad * 4;
#pragma unroll
            for (int r = 0; r < 4; ++r) {
                int m = mbase + r;
                u16 h = f2b(acc[im][in][r] + bv);
                if (n < 128) {
                    KVh[((size_t)(n >> 4) * 2880 + m) * 16 + (n & 15)] = h;
                } else {
                    int ch = n - 128, bb2, tok;
                    if (m < 2304) { bb2 = m / 576; tok = m % 576; }
                    else { int r2 = m - 2304; bb2 = r2 / 144; tok = 576 + r2 % 144; }
                    VTg[((size_t)(bb2 * 128 + ch)) * 720 + tok] = h;
                }
            }
        }
    }
}

// ---------------------------------------------------------------------------
// Kernel 3: fused attention, 2 windows/block, 288 blocks x 512 thr (8 waves,
// wave = head). Barrier-free pooled loop: wave-private single-buffer KP
// (per-wave DS ops in-order), flat 2-deep prefetch. 2 barriers total.
// launch_bounds (512,2): empirically 2nd arg acts as blocks/CU -> 16
// waves/CU -> 128 VGPR cap (64 cap at (512,4) caused v16's 208MB spill).
__global__ __launch_bounds__(512, 2) void k_attn_fused(
    const float* __restrict__ F,
    const u16* __restrict__ Xt,
    const float* __restrict__ MuRs,
    const u16* __restrict__ KVh,     // [8][2880][16] head-major
    const u16* __restrict__ VTg,
    const u16* __restrict__ Wb,      // [qwb|kvwb|owb|lnwb|lnbb]
    const float* __restrict__ qb,
    const float* __restrict__ kvb,
    const float* __restrict__ ob,
    float* __restrict__ Out)
{
    __shared__ u16 KP[8][64][16];       // wave-private K tile (16 KB)
    __shared__ u16 VtW[8][2][16][68];   // per-wave/window local V^T (34.8 KB)

    const u16* qwb  = Wb;
    const u16* kvwb = Wb + 16384;
    const u16* owb  = Wb + 49152;
    const u16* lnwb = Wb + 65536;
    const u16* lnbb = Wb + 65664;
    u16* Atp = &VtW[0][0][0][0];        // overlay [2][16][136] = 4352 u16

    // Bijective XCD swizzle: 288 = 8 xcd x 36. xcd -> one batch-half.
    int blk = blockIdx.x;
    int xcd = blk & 7, jj = blk >> 3;   // jj 0..35
    int b = xcd >> 1;
    int wr = (xcd & 1) * 6 + jj / 6;
    int wcp = jj % 6;                   // windows wc = 2*wcp + {0,1}

    int t = threadIdx.x;
    int lane = t & 63, wave = t >> 6, n15 = lane & 15, quad = lane >> 4;
    v8s zf8 = {};
    v4f zz4 = {0.f, 0.f, 0.f, 0.f};
    const float QSCALE = 0.25f * 1.44269504f;

    u16* KPw = &KP[wave][0][0];
    const u16* kwave = KVh + (size_t)wave * 46080;   // this head's K rows
    const u16* vrow0 = VTg + (size_t)b * 92160
                     + (size_t)(wave * 16 + n15) * 720 + quad * 4;

    // --- issue tile-0 K slice (contiguous 2KB/wave) + V fragments first ---
    v8s kN0, kN1;
    {
        const u16* s = kwave + (size_t)(b * 576 + lane) * 16;
        kN0 = *(const v8s_am*)s; kN1 = *(const v8s_am*)(s + 8);
    }
    v4s vpC[4], vpN[4];
#pragma unroll
    for (int g = 0; g < 4; ++g) vpC[g] = *(const v4s_am*)(vrow0 + g * 16);

    // --- LN + Q projection per window ---
    v4s qf[2];
#pragma unroll
    for (int wi = 0; wi < 2; ++wi) {
        int wc = wcp * 2 + wi;
        int qh = wr * 4 + (n15 >> 2), qw_ = wc * 4 + (n15 & 3);
        int qpix = b * 2304 + qh * 48 + qw_;
        float mu = MuRs[qpix * 2], rstd = MuRs[qpix * 2 + 1];
        v8s xln[4];
#pragma unroll
        for (int kc = 0; kc < 4; ++kc) {
            v8s x  = *(const v8s_am*)&Xt[(size_t)qpix * 128 + kc * 32 + quad * 8];
            v8s lw = *(const v8s_am*)&lnwb[kc * 32 + quad * 8];
            v8s lb = *(const v8s_am*)&lnbb[kc * 32 + quad * 8];
            v8s y;
#pragma unroll
            for (int j = 0; j < 8; ++j)
                y[j] = (short)f2b((b2f((u16)x[j]) - mu) * rstd * b2f((u16)lw[j]) + b2f((u16)lb[j]));
            xln[kc] = y;
        }
        int n0 = wave * 16;
        v4f qacc = zz4;
#pragma unroll
        for (int kc = 0; kc < 4; ++kc) {
            v8s aw = *(const v8s_am*)&qwb[((size_t)(n0 + n15)) * 128 + kc * 32 + quad * 8];
            qacc = MFMA_BF16(aw, xln[kc], qacc);
        }
        v4s q4;
#pragma unroll
        for (int r = 0; r < 4; ++r)
            q4[r] = (short)f2b((qacc[r] + qb[n0 + quad * 4 + r]) * QSCALE);
        qf[wi] = q4;
    }

    // --- local K/V projection per window (this wave's head only) ---
    v4s kfloc[2][4];
#pragma unroll
    for (int wi = 0; wi < 2; ++wi) {
        int wc = wcp * 2 + wi;
#pragma unroll
        for (int g = 0; g < 4; ++g) {
            int tl = g * 16 + n15;
            int fh = tl >> 3, fw = tl & 7;
            int hh = wr * 4 - 2 + fh, ww = wc * 4 - 2 + fw;
            bool valid = (hh >= 0 && hh < 48 && ww >= 0 && ww < 48);
            size_t arow = (size_t)(b * 2304 + hh * 48 + ww) * 128;
            v8s xb[4];
#pragma unroll
            for (int kc = 0; kc < 4; ++kc) {
                v8s v = zf8;
                if (valid) v = *(const v8s_am*)&Xt[arow + kc * 32 + quad * 8];
                xb[kc] = v;
            }
#pragma unroll
            for (int s = 0; s < 2; ++s) {    // s=0: K strip, s=1: V strip
                int sbase = s * 128 + wave * 16;
                v4f acc = zz4;
#pragma unroll
                for (int kc = 0; kc < 4; ++kc) {
                    v8s aw = *(const v8s_am*)&kvwb[((size_t)(sbase + n15)) * 128 + kc * 32 + quad * 8];
                    acc = MFMA_BF16(aw, xb[kc], acc);
                }
                if (s == 0) {
                    v4s k4;
#pragma unroll
                    for (int r = 0; r < 4; ++r)
                        k4[r] = (short)f2b(acc[r] + kvb[sbase + quad * 4 + r]);
                    kfloc[wi][g] = k4;
                } else {
#pragma unroll
                    for (int r = 0; r < 4; ++r)
                        VtW[wave][wi][quad * 4 + r][g * 16 + n15] =
                            f2b(acc[r] + kvb[sbase + quad * 4 + r]);
                }
            }
        }
    }

    v4f oacc[2] = {};
    float ls0 = 0.f, ls1 = 0.f;

    // --- local chunk (K frags in regs, V from wave-private LDS slice) ---
    asm volatile("s_waitcnt lgkmcnt(0)" ::: "memory");
#pragma unroll
    for (int wi = 0; wi < 2; ++wi) {
#pragma unroll
        for (int g = 0; g < 4; ++g) {
            v4f St = MFMA16(kfloc[wi][g], qf[wi], zz4);  // S^T[tok][q=n15]
            float p0 = EXP2(St[0]), p1 = EXP2(St[1]);
            float p2 = EXP2(St[2]), p3 = EXP2(St[3]);
            if (wi == 0) ls0 += (p0 + p1) + (p2 + p3);
            else         ls1 += (p0 + p1) + (p2 + p3);
            v4s pk = {(short)f2b(p0), (short)f2b(p1), (short)f2b(p2), (short)f2b(p3)};
            v4s vf = *(const v4s_am*)&VtW[wave][wi][n15][g * 16 + quad * 4];
            oacc[wi] = MFMA16(vf, pk, oacc[wi]);         // O^T[ch][q=n15]
        }
    }
    // All VtW reads done -> later At-overlay writes can't race them.
    __syncthreads();    // barrier 1 (also drains tile-0 loads)

    // --- F-residual prefetch (cold HBM, used only in epilogue) ---
    float fres[2][4];
#pragma unroll
    for (int wi = 0; wi < 2; ++wi) {
        int wc = wcp * 2 + wi;
        int c = wave * 16 + n15;
#pragma unroll
        for (int r = 0; r < 4; ++r) {
            int pix = quad * 4 + r;
            int hh = wr * 4 + (pix >> 2), ww_ = wc * 4 + (pix & 3);
            fres[wi][r] = F[((size_t)(b * 128 + c)) * 2304 + hh * 48 + ww_];
        }
    }

    // --- stage tile 0 (kN complete: drained by barrier 1) ---
    *(v8s_am*)&KPw[lane * 16]     = kN0;
    *(v8s_am*)&KPw[lane * 16 + 8] = kN1;
    // issue tile-1 K + V
    {
        const u16* s = kwave + (size_t)(b * 576 + 64 + lane) * 16;
        kN0 = *(const v8s_am*)s; kN1 = *(const v8s_am*)(s + 8);
    }
#pragma unroll
    for (int g = 0; g < 4; ++g) vpN[g] = *(const v4s_am*)(vrow0 + 64 + g * 16);

    // --- pooled tiles 0..11: barrier-free, wave-private single buffer ---
#pragma unroll
    for (int tb = 0; tb <= 11; ++tb) {
        // read this tile's K fragments (tile tb, written last round)
        v4s kf[4];
#pragma unroll
        for (int g = 0; g < 4; ++g)
            kf[g] = *(const v4s_am*)&KPw[(g * 16 + n15) * 16 + quad * 4];
        // overwrite KP with tile tb+1 (same-wave DS ops are in-order)
        if (tb < 11) {
            *(v8s_am*)&KPw[lane * 16]     = kN0;
            *(v8s_am*)&KPw[lane * 16 + 8] = kN1;
            if (tb < 10) {   // issue K(tb+2)
                int t2 = tb + 2;
                int row = (t2 < 9) ? (b * 576 + t2 * 64 + lane)
                                   : (2304 + b * 144 + (t2 - 9) * 64 + lane);
                if (t2 == 11) row = min(2304 + b * 144 + 128 + lane, 2879);
                const u16* s = kwave + (size_t)row * 16;
                kN0 = *(const v8s_am*)s; kN1 = *(const v8s_am*)(s + 8);
            }
        }
        // compute tile tb (tb==11: only 16 tokens -> g=0)
#pragma unroll
        for (int g = 0; g < ((tb == 11) ? 1 : 4); ++g) {
            v4f St0 = MFMA16(kf[g], qf[0], zz4);
            v4f St1 = MFMA16(kf[g], qf[1], zz4);
            float a0 = EXP2(St0[0]), a1 = EXP2(St0[1]), a2 = EXP2(St0[2]), a3 = EXP2(St0[3]);
            float b0 = EXP2(St1[0]), b1 = EXP2(St1[1]), b2 = EXP2(St1[2]), b3 = EXP2(St1[3]);
            ls0 += (a0 + a1) + (a2 + a3);
            ls1 += (b0 + b1) + (b2 + b3);
            v4s pk0 = {(short)f2b(a0), (short)f2b(a1), (short)f2b(a2), (short)f2b(a3)};
            v4s pk1 = {(short)f2b(b0), (short)f2b(b1), (short)f2b(b2), (short)f2b(b3)};
            oacc[0] = MFMA16(vpC[g], pk0, oacc[0]);
            oacc[1] = MFMA16(vpC[g], pk1, oacc[1]);
        }
        // rotate V regs and issue V(tb+2)
        if (tb < 11) {
#pragma unroll
            for (int g = 0; g < 4; ++g) vpC[g] = vpN[g];
            if (tb < 10) {
                int t2 = tb + 2;
#pragma unroll
                for (int g = 0; g < 4; ++g) {
                    int off = (t2 == 11) ? 704 : (t2 * 64 + g * 16);
                    vpN[g] = *(const v4s_am*)(vrow0 + off);
                }
            }
        }
    }

    // --- l reduce; write attended into At (overlay on VtW[0..1]) ---
#pragma unroll
    for (int wi = 0; wi < 2; ++wi) {
        float ls = wi == 0 ? ls0 : ls1;
        ls += __shfl_xor(ls, 16);
        ls += __shfl_xor(ls, 32);
        float inv = 1.f / ls;
        v4s a4 = {(short)f2b(oacc[wi][0] * inv), (short)f2b(oacc[wi][1] * inv),
                  (short)f2b(oacc[wi][2] * inv), (short)f2b(oacc[wi][3] * inv)};
        *(v4s_am*)&Atp[wi * 2176 + n15 * 136 + wave * 16 + quad * 4] = a4;
    }
    __syncthreads();    // barrier 2: At complete before out-proj reads

    // --- out projection (16 out-ch per wave) + bias + residual, NCHW ---
#pragma unroll
    for (int wi = 0; wi < 2; ++wi) {
        int wc = wcp * 2 + wi;
        int n0 = wave * 16;
        v4f oa = zz4;
#pragma unroll
        for (int kc = 0; kc < 4; ++kc) {
            v8s af = *(const v8s_am*)&Atp[wi * 2176 + n15 * 136 + kc * 32 + quad * 8];
            v8s bf = *(const v8s_am*)&owb[((size_t)(n0 + n15)) * 128 + kc * 32 + quad * 8];
            oa = MFMA_BF16(af, bf, oa);
        }
        int c = n0 + n15;
        float bv = ob[c];
#pragma unroll
        for (int r = 0; r < 4; ++r) {
            int pix = quad * 4 + r;
            int hh = wr * 4 + (pix >> 2), ww_ = wc * 4 + (pix & 3);
            size_t idx = ((size_t)(b * 128 + c)) * 2304 + hh * 48 + ww_;
            Out[idx] = oa[r] + bv + fres[wi][r];
        }
    }
}

// ---------------------------------------------------------------------------
extern "C" void kernel_launch(void* const* d_in, const int* in_sizes, int n_in,
                              void* d_out, int out_size, void* d_ws, size_t ws_size,
                              hipStream_t stream)
{
    const float* F   = (const float*)d_in[0];
    const float* lnw = (const float*)d_in[1];
    const float* lnb = (const float*)d_in[2];
    const float* qw  = (const float*)d_in[3];
    const float* qb  = (const float*)d_in[4];
    const float* kvw = (const float*)d_in[5];
    const float* kvb = (const float*)d_in[6];
    const float* ow  = (const float*)d_in[7];
    const float* ob  = (const float*)d_in[8];
    float* Out = (float*)d_out;

    u16* ws    = (u16*)d_ws;
    u16* Xt    = ws;                    // 9216*128  = 1,179,648 u16
    u16* Pml   = Xt + 9216 * 128;       // 2880*128  =   368,640
    u16* KVh   = Pml + 2880 * 128;      // 8*2880*16 =   368,640 (head-major)
    u16* VTg   = KVh + 8 * 2880 * 16;   // 4*128*720 =   368,640
    u16* Wb    = VTg + 4 * 128 * 720;   // 65,792 [qwb|kvwb|owb|lnwb|lnbb]
    float* MuRs = (float*)(Wb + 65792); // 9216*2 fp32
    // total: ~4.77 MiB
    u16* kvwb = Wb + 16384;

    k_prep<<<484, 256, 0, stream>>>(F, qw, kvw, ow, lnw, lnb, Xt, Wb, MuRs, Pml);
    k_gemm_kv<<<dim3(45, 4), 256, 0, stream>>>(Pml, kvwb, kvb, KVh, VTg);
    k_attn_fused<<<288, 512, 0, stream>>>(F, Xt, MuRs, KVh, VTg, Wb,
                                          qb, kvb, ob, Out);
}

// Round 10
// 129.103 us; speedup vs baseline: 1.6344x; 1.4633x over previous
//
#include <hip/hip_runtime.h>

// FocalSelfAttention on MI355X. fp32 I/O, bf16 MFMA compute, fp32 accum.
// B=4, C=128, H=W=48, WS=4 -> 144 windows/batch, 16 q/window, NH=8, hd=16,
// Nkv = 64 local + 720 pooled.
//
// v18: barrier-free pooled loop on the v12 SHAPE (576 blocks x 512 thr,
// 1 window/block, wave = head). v17 proved launch_bounds 2nd arg acts as
// blocks/CU ((512,2) -> 128 VGPR cap) but the 2-window kernel's state still
// exceeded 128 -> spill. The 1-window shape ran at VGPR 48 (v12); adding
// wave-private single-buffer KP staging (+~10 regs) leaves huge headroom.
//  * K head-major KVh[8][2880][16]: a wave's per-tile K slice is ONE
//    contiguous 2KB load (64 lanes x 32B).
//  * Pooled loop: read tile tb from KP[wave][64][16], ds_write tile tb+1
//    (per-wave DS ops in-order -> no barrier, no dbuf), prefetch K(tb+2)
//    into regs. V fragments loaded at use (as v12). 0 barriers in loop,
//    2 in kernel. LDS 33.4 KB.
//  * prep / gemm_kv: v12 structure (best measured rest), gemm K store
//    changed to head-major only.

typedef unsigned short u16;
typedef short v8s __attribute__((ext_vector_type(8)));
typedef v8s __attribute__((may_alias)) v8s_am;
typedef short v4s __attribute__((ext_vector_type(4)));
typedef v4s __attribute__((may_alias)) v4s_am;
typedef float v4f __attribute__((ext_vector_type(4)));

#define MFMA_BF16(a, b, c) __builtin_amdgcn_mfma_f32_16x16x32_bf16(a, b, c, 0, 0, 0)

#if __has_builtin(__builtin_amdgcn_mfma_f32_16x16x16bf16_1k)
#define MFMA16(a, b, c) __builtin_amdgcn_mfma_f32_16x16x16bf16_1k(a, b, c, 0, 0, 0)
#else
static __device__ __forceinline__ v4f mfma16_fb(v4s a, v4s b, v4f c) {
    v8s a8 = {a[0], a[1], a[2], a[3], 0, 0, 0, 0};
    v8s b8 = {b[0], b[1], b[2], b[3], 0, 0, 0, 0};
    return MFMA_BF16(a8, b8, c);
}
#define MFMA16(a, b, c) mfma16_fb(a, b, c)
#endif

#if __has_builtin(__builtin_amdgcn_exp2f)
#define EXP2(x) __builtin_amdgcn_exp2f(x)
#else
#define EXP2(x) exp2f(x)
#endif

__device__ __forceinline__ float b2f(u16 u) {
    union { unsigned int i; float f; } x;
    x.i = ((unsigned int)u) << 16;
    return x.f;
}
__device__ __forceinline__ u16 f2b(float f) {
    union { float f; unsigned int i; } x;
    x.f = f;
    unsigned int u = x.i;
    return (u16)((u + 0x7fffu + ((u >> 16) & 1u)) >> 16);
}

// ---------------------------------------------------------------------------
// Kernel 1: blocks 0..287 transpose F->Xt + LN stats; 288..303 weights;
// 304..483 pooled tokens -> Pml. (v12 structure, best measured.)
__global__ __launch_bounds__(256) void k_prep(
    const float* __restrict__ F,
    const float* __restrict__ qw, const float* __restrict__ kvw,
    const float* __restrict__ ow,
    const float* __restrict__ lnw, const float* __restrict__ lnb,
    u16* __restrict__ Xt, u16* __restrict__ Wb, float* __restrict__ MuRs,
    u16* __restrict__ Pml)
{
    int blk = blockIdx.x;
    int t = threadIdx.x;
    if (blk >= 304) {   // ---- pool part: 180 blocks ----
        int gid = (blk - 304) * 256 + t;
        int row = gid >> 4;
        int seg = gid & 15;
        v8s outv;
        if (row < 2304) {        // mid: avg 2x2
            int b = row / 576, r = row % 576;
            int i = r / 24, j = r % 24;
#pragma unroll
            for (int jc = 0; jc < 8; ++jc) {
                int c = seg * 8 + jc;
                const float* src = F + ((size_t)(b * 128 + c)) * 2304 + (2 * i) * 48 + 2 * j;
                float2 a = *(const float2*)src;
                float2 d = *(const float2*)(src + 48);
                outv[jc] = (short)f2b((a.x + a.y + d.x + d.y) * 0.25f);
            }
        } else {                 // glo: avg 4x4
            int r2 = row - 2304;
            int b = r2 / 144, r = r2 % 144;
            int i = r / 12, j = r % 12;
#pragma unroll
            for (int jc = 0; jc < 8; ++jc) {
                int c = seg * 8 + jc;
                const float* src = F + ((size_t)(b * 128 + c)) * 2304 + (4 * i) * 48 + 4 * j;
                float s = 0.f;
#pragma unroll
                for (int di = 0; di < 4; ++di) {
                    float4 v = *(const float4*)(src + di * 48);
                    s += (v.x + v.y) + (v.z + v.w);
                }
                outv[jc] = (short)f2b(s * 0.0625f);
            }
        }
        *(v8s_am*)&Pml[((size_t)row) * 128 + seg * 8] = outv;
        return;
    }
    if (blk >= 288) {   // ---- weight conversion: 16 blocks ----
        int base = (blk - 288) * 4096 + t * 16;
#pragma unroll
        for (int i = 0; i < 4; ++i) {
            int idx = base + i * 4;
            const float* src; int off;
            if (idx < 16384)      { src = qw;  off = idx; }
            else if (idx < 49152) { src = kvw; off = idx - 16384; }
            else                  { src = ow;  off = idx - 49152; }
            float4 v = *(const float4*)(src + off);
            unsigned long long packed =
                (unsigned long long)f2b(v.x) |
                ((unsigned long long)f2b(v.y) << 16) |
                ((unsigned long long)f2b(v.z) << 32) |
                ((unsigned long long)f2b(v.w) << 48);
            *(unsigned long long*)(Wb + idx) = packed;
        }
        if (blk == 288) {
            Wb[65536 + t] = f2b(t < 128 ? lnw[t] : lnb[t - 128]);
        }
        return;
    }
    // ---- transpose + LN stats: 288 blocks ----
    __shared__ u16 X[128][34];
    int b = blk / 72;
    int p0 = (blk % 72) * 32;
#pragma unroll 4
    for (int i = 0; i < 16; ++i) {
        int c = i * 8 + (t >> 5);
        int pix = t & 31;
        X[c][pix] = f2b(F[((size_t)(b * 128 + c)) * 2304 + p0 + pix]);
    }
    __syncthreads();
    int pix = t >> 3;
    int c0 = (t & 7) * 16;
    size_t row = (size_t)(b * 2304 + p0 + pix) * 128;
    float s = 0.f, s2 = 0.f;
#pragma unroll
    for (int sg = 0; sg < 2; ++sg) {
        v8s raw;
#pragma unroll
        for (int j = 0; j < 8; ++j) {
            u16 u = X[c0 + sg * 8 + j][pix];
            raw[j] = (short)u;
            float v = b2f(u);
            s += v; s2 += v * v;
        }
        *(v8s_am*)&Xt[row + c0 + sg * 8] = raw;
    }
    s += __shfl_xor(s, 1);  s2 += __shfl_xor(s2, 1);
    s += __shfl_xor(s, 2);  s2 += __shfl_xor(s2, 2);
    s += __shfl_xor(s, 4);  s2 += __shfl_xor(s2, 4);
    if ((t & 7) == 0) {
        float mean = s * (1.f / 128.f);
        float var = s2 * (1.f / 128.f) - mean * mean;
        float rstd = rsqrtf(var + 1e-5f);
        MuRs[(b * 2304 + p0 + pix) * 2]     = mean;
        MuRs[(b * 2304 + p0 + pix) * 2 + 1] = rstd;
    }
}

// ---------------------------------------------------------------------------
// Kernel 2: mid/glo K/V projection from Pml (v12 structure).
// K -> HEAD-MAJOR KVh[8][2880][16]; V -> VTg[b][128 ch][720 tok].
__global__ __launch_bounds__(256) void k_gemm_kv(
    const u16* __restrict__ Pml,
    const u16* __restrict__ W,
    const float* __restrict__ bias,
    u16* __restrict__ KVh,
    u16* __restrict__ VTg)
{
    __shared__ u16 Al[64][136];
    __shared__ u16 Wl[64][136];
    int tm = blockIdx.x * 64, tn = blockIdx.y * 64;
    int t = threadIdx.x;
    {
        int seg = t & 15, r0 = t >> 4;
#pragma unroll
        for (int i = 0; i < 4; ++i) {
            int r = r0 + 16 * i;
            *(v8s_am*)&Al[r][seg * 8] = *(const v8s_am*)&Pml[((size_t)(tm + r)) * 128 + seg * 8];
            *(v8s_am*)&Wl[r][seg * 8] = *(const v8s_am*)&W[((size_t)(tn + r)) * 128 + seg * 8];
        }
    }
    __syncthreads();
    int lane = t & 63, wave = t >> 6;
    int n15 = lane & 15, quad = lane >> 4;
    int wm = (wave & 1) * 32, wn = (wave >> 1) * 32;
    v4f acc[2][2] = {};
#pragma unroll
    for (int kc = 0; kc < 4; ++kc) {
        v8s a[2], bb[2];
#pragma unroll
        for (int im = 0; im < 2; ++im)
            a[im] = *(const v8s_am*)&Al[wm + im * 16 + n15][kc * 32 + quad * 8];
#pragma unroll
        for (int in = 0; in < 2; ++in)
            bb[in] = *(const v8s_am*)&Wl[wn + in * 16 + n15][kc * 32 + quad * 8];
#pragma unroll
        for (int im = 0; im < 2; ++im)
#pragma unroll
            for (int in = 0; in < 2; ++in)
                acc[im][in] = MFMA_BF16(a[im], bb[in], acc[im][in]);
    }
#pragma unroll
    for (int in = 0; in < 2; ++in) {
        int n = tn + wn + in * 16 + n15;
        float bv = bias[n];
#pragma unroll
        for (int im = 0; im < 2; ++im) {
            int mbase = tm + wm + im * 16 + quad * 4;
#pragma unroll
            for (int r = 0; r < 4; ++r) {
                int m = mbase + r;
                u16 h = f2b(acc[im][in][r] + bv);
                if (n < 128) {
                    KVh[((size_t)(n >> 4) * 2880 + m) * 16 + (n & 15)] = h;
                } else {
                    int ch = n - 128, bb2, tok;
                    if (m < 2304) { bb2 = m / 576; tok = m % 576; }
                    else { int r2 = m - 2304; bb2 = r2 / 144; tok = 576 + r2 % 144; }
                    VTg[((size_t)(bb2 * 128 + ch)) * 720 + tok] = h;
                }
            }
        }
    }
}

// ---------------------------------------------------------------------------
// Kernel 3: fused attention. 576 blocks x 512 thr (8 waves), wave = head,
// 1 window/block (v12 shape). Barrier-free pooled loop via wave-private
// single-buffer KP (per-wave in-order DS). 2 barriers total. (512,2) ->
// 128 VGPR cap (proven v17); demand ~90 -> no spill.
__global__ __launch_bounds__(512, 2) void k_attn_fused(
    const float* __restrict__ F,
    const u16* __restrict__ Xt,
    const float* __restrict__ MuRs,
    const u16* __restrict__ KVh,     // [8][2880][16] head-major
    const u16* __restrict__ VTg,
    const u16* __restrict__ Wb,      // [qwb|kvwb|owb|lnwb|lnbb]
    const float* __restrict__ qb,
    const float* __restrict__ kvb,
    const float* __restrict__ ob,
    float* __restrict__ Out)
{
    __shared__ u16 KP[8][64][16];    // wave-private K tile (16 KB)
    __shared__ u16 VtW[8][16][68];   // per-wave local V^T (17.4 KB)

    const u16* qwb  = Wb;
    const u16* kvwb = Wb + 16384;
    const u16* owb  = Wb + 49152;
    const u16* lnwb = Wb + 65536;
    const u16* lnbb = Wb + 65664;
    u16* Atp = &VtW[0][0][0];        // overlay [16][136] = 2176 u16

    // Bijective XCD swizzle: xcd = blk&7 -> one batch-half per XCD.
    int blk = blockIdx.x;
    int xcd = blk & 7, jj = blk >> 3;   // jj 0..71
    int b = xcd >> 1;
    int wr = (xcd & 1) * 6 + jj / 12;
    int wc = jj % 12;

    int t = threadIdx.x;
    int lane = t & 63, wave = t >> 6, n15 = lane & 15, quad = lane >> 4;
    v8s zf8 = {};
    v4f zz4 = {0.f, 0.f, 0.f, 0.f};
    const float QSCALE = 0.25f * 1.44269504f;

    u16* KPw = &KP[wave][0][0];
    const u16* kwave = KVh + (size_t)wave * 46080;   // this head's K rows
    const u16* vrow0 = VTg + (size_t)b * 92160
                     + (size_t)(wave * 16 + n15) * 720 + quad * 4;

    // --- issue tile-0 K slice (contiguous 2KB/wave) immediately ---
    v8s kN0, kN1;
    {
        const u16* s = kwave + (size_t)(b * 576 + lane) * 16;
        kN0 = *(const v8s_am*)s; kN1 = *(const v8s_am*)(s + 8);
    }

    // --- per-lane LN'd window token B-fragments (tok = n15) ---
    int qh = wr * 4 + (n15 >> 2), qw_ = wc * 4 + (n15 & 3);
    int qpix = b * 2304 + qh * 48 + qw_;
    float mu = MuRs[qpix * 2], rstd = MuRs[qpix * 2 + 1];
    v8s xln[4];
#pragma unroll
    for (int kc = 0; kc < 4; ++kc) {
        v8s x  = *(const v8s_am*)&Xt[(size_t)qpix * 128 + kc * 32 + quad * 8];
        v8s lw = *(const v8s_am*)&lnwb[kc * 32 + quad * 8];
        v8s lb = *(const v8s_am*)&lnbb[kc * 32 + quad * 8];
        v8s y;
#pragma unroll
        for (int j = 0; j < 8; ++j)
            y[j] = (short)f2b((b2f((u16)x[j]) - mu) * rstd * b2f((u16)lw[j]) + b2f((u16)lb[j]));
        xln[kc] = y;
    }

    // --- Q projection TRANSPOSED for head=wave: D[d=quad*4+r][q=n15] ---
    v4s qf;
    {
        int n0 = wave * 16;
        v4f qacc = zz4;
#pragma unroll
        for (int kc = 0; kc < 4; ++kc) {
            v8s aw = *(const v8s_am*)&qwb[((size_t)(n0 + n15)) * 128 + kc * 32 + quad * 8];
            qacc = MFMA_BF16(aw, xln[kc], qacc);
        }
#pragma unroll
        for (int r = 0; r < 4; ++r)
            qf[r] = (short)f2b((qacc[r] + qb[n0 + quad * 4 + r]) * QSCALE);
    }

    // --- local K/V projection TRANSPOSED (this wave's head only) ---
    v4s kfloc[4];
#pragma unroll
    for (int g = 0; g < 4; ++g) {
        int tl = g * 16 + n15;
        int fh = tl >> 3, fw = tl & 7;
        int hh = wr * 4 - 2 + fh, ww = wc * 4 - 2 + fw;
        bool valid = (hh >= 0 && hh < 48 && ww >= 0 && ww < 48);
        size_t arow = (size_t)(b * 2304 + hh * 48 + ww) * 128;
        v8s xb[4];
#pragma unroll
        for (int kc = 0; kc < 4; ++kc) {
            v8s v = zf8;
            if (valid) v = *(const v8s_am*)&Xt[arow + kc * 32 + quad * 8];
            xb[kc] = v;
        }
#pragma unroll
        for (int s = 0; s < 2; ++s) {    // s=0: K strip, s=1: V strip
            int sbase = s * 128 + wave * 16;
            v4f acc = zz4;
#pragma unroll
            for (int kc = 0; kc < 4; ++kc) {
                v8s aw = *(const v8s_am*)&kvwb[((size_t)(sbase + n15)) * 128 + kc * 32 + quad * 8];
                acc = MFMA_BF16(aw, xb[kc], acc);
            }
            if (s == 0) {
                v4s k4;
#pragma unroll
                for (int r = 0; r < 4; ++r)
                    k4[r] = (short)f2b(acc[r] + kvb[sbase + quad * 4 + r]);
                kfloc[g] = k4;
            } else {
#pragma unroll
                for (int r = 0; r < 4; ++r)
                    VtW[wave][quad * 4 + r][g * 16 + n15] =
                        f2b(acc[r] + kvb[sbase + quad * 4 + r]);
            }
        }
    }

    v4f oacc = zz4;
    float ls = 0.f;

    // --- local chunk (K frags in regs, V from wave-private LDS slice) ---
    asm volatile("s_waitcnt lgkmcnt(0)" ::: "memory");
#pragma unroll
    for (int g = 0; g < 4; ++g) {
        v4f St = MFMA16(kfloc[g], qf, zz4);     // S^T[tok=quad*4+r][q=n15]
        float p0 = EXP2(St[0]), p1 = EXP2(St[1]);
        float p2 = EXP2(St[2]), p3 = EXP2(St[3]);
        ls += (p0 + p1) + (p2 + p3);
        v4s pk = {(short)f2b(p0), (short)f2b(p1), (short)f2b(p2), (short)f2b(p3)};
        v4s vf = *(const v4s_am*)&VtW[wave][n15][g * 16 + quad * 4];
        oacc = MFMA16(vf, pk, oacc);            // O^T[ch=quad*4+r][q=n15]
    }
    // All VtW reads done -> later At-overlay writes can't race them.
    __syncthreads();    // barrier 1

    // --- stage tile 0; issue tile-1 K ---
    *(v8s_am*)&KPw[lane * 16]     = kN0;
    *(v8s_am*)&KPw[lane * 16 + 8] = kN1;
    {
        const u16* s = kwave + (size_t)(b * 576 + 64 + lane) * 16;
        kN0 = *(const v8s_am*)s; kN1 = *(const v8s_am*)(s + 8);
    }

    // --- pooled tiles 0..10: barrier-free, wave-private single buffer ---
    for (int tb = 0; tb <= 10; ++tb) {
        // read tile tb's K fragments (DS in-order: reads precede the write)
        v4s kf[4];
#pragma unroll
        for (int g = 0; g < 4; ++g)
            kf[g] = *(const v4s_am*)&KPw[(g * 16 + n15) * 16 + quad * 4];
        // overwrite KP with tile tb+1
        *(v8s_am*)&KPw[lane * 16]     = kN0;
        *(v8s_am*)&KPw[lane * 16 + 8] = kN1;
        if (tb < 10) {   // issue K(tb+2): tiles 2..11
            int t2 = tb + 2;
            int row = (t2 < 9) ? (b * 576 + t2 * 64 + lane)
                               : (2304 + b * 144 + (t2 - 9) * 64 + lane);
            if (t2 == 11) row = 2304 + b * 144 + 128 + n15;  // 16 rows, dup x4
            const u16* s = kwave + (size_t)row * 16;
            kN0 = *(const v8s_am*)s; kN1 = *(const v8s_am*)(s + 8);
        }
        // V fragments at use (L2-hot VTg)
        v4s vp[4];
#pragma unroll
        for (int g = 0; g < 4; ++g)
            vp[g] = *(const v4s_am*)(vrow0 + tb * 64 + g * 16);
        // compute tile tb
#pragma unroll
        for (int g = 0; g < 4; ++g) {
            v4f St = MFMA16(kf[g], qf, zz4);
            float p0 = EXP2(St[0]), p1 = EXP2(St[1]);
            float p2 = EXP2(St[2]), p3 = EXP2(St[3]);
            ls += (p0 + p1) + (p2 + p3);
            v4s pk = {(short)f2b(p0), (short)f2b(p1), (short)f2b(p2), (short)f2b(p3)};
            oacc = MFMA16(vp[g], pk, oacc);
        }
    }
    // --- tile 11: 16 toks (glo 128..143), staged at tb==10 ---
    {
        v4s kf = *(const v4s_am*)&KPw[n15 * 16 + quad * 4];
        v4s vf = *(const v4s_am*)(vrow0 + 704);
        v4f St = MFMA16(kf, qf, zz4);
        float p0 = EXP2(St[0]), p1 = EXP2(St[1]);
        float p2 = EXP2(St[2]), p3 = EXP2(St[3]);
        ls += (p0 + p1) + (p2 + p3);
        v4s pk = {(short)f2b(p0), (short)f2b(p1), (short)f2b(p2), (short)f2b(p3)};
        oacc = MFMA16(vf, pk, oacc);
    }

    // --- l reduce (across quads); write attended into At overlay ---
    ls += __shfl_xor(ls, 16);
    ls += __shfl_xor(ls, 32);
    {
        float inv = 1.f / ls;
        v4s a4 = {(short)f2b(oacc[0] * inv), (short)f2b(oacc[1] * inv),
                  (short)f2b(oacc[2] * inv), (short)f2b(oacc[3] * inv)};
        *(v4s_am*)&Atp[n15 * 136 + wave * 16 + quad * 4] = a4;
    }
    __syncthreads();    // barrier 2: At complete before out-proj reads

    // --- out projection (16 out-ch per wave) + bias + residual, NCHW ---
    {
        int n0 = wave * 16;
        v4f oa = zz4;
#pragma unroll
        for (int kc = 0; kc < 4; ++kc) {
            v8s af = *(const v8s_am*)&Atp[n15 * 136 + kc * 32 + quad * 8];
            v8s bf = *(const v8s_am*)&owb[((size_t)(n0 + n15)) * 128 + kc * 32 + quad * 8];
            oa = MFMA_BF16(af, bf, oa);
        }
        int c = n0 + n15;
        float bv = ob[c];
#pragma unroll
        for (int r = 0; r < 4; ++r) {
            int pix = quad * 4 + r;
            int hh = wr * 4 + (pix >> 2), ww_ = wc * 4 + (pix & 3);
            size_t idx = ((size_t)(b * 128 + c)) * 2304 + hh * 48 + ww_;
            Out[idx] = oa[r] + bv + F[idx];
        }
    }
}

// ---------------------------------------------------------------------------
extern "C" void kernel_launch(void* const* d_in, const int* in_sizes, int n_in,
                              void* d_out, int out_size, void* d_ws, size_t ws_size,
                              hipStream_t stream)
{
    const float* F   = (const float*)d_in[0];
    const float* lnw = (const float*)d_in[1];
    const float* lnb = (const float*)d_in[2];
    const float* qw  = (const float*)d_in[3];
    const float* qb  = (const float*)d_in[4];
    const float* kvw = (const float*)d_in[5];
    const float* kvb = (const float*)d_in[6];
    const float* ow  = (const float*)d_in[7];
    const float* ob  = (const float*)d_in[8];
    float* Out = (float*)d_out;

    u16* ws    = (u16*)d_ws;
    u16* Xt    = ws;                    // 9216*128  = 1,179,648 u16
    u16* Pml   = Xt + 9216 * 128;       // 2880*128  =   368,640
    u16* KVh   = Pml + 2880 * 128;      // 8*2880*16 =   368,640 (head-major)
    u16* VTg   = KVh + 8 * 2880 * 16;   // 4*128*720 =   368,640
    u16* Wb    = VTg + 4 * 128 * 720;   // 65,792 [qwb|kvwb|owb|lnwb|lnbb]
    float* MuRs = (float*)(Wb + 65792); // 9216*2 fp32
    // total: ~4.77 MiB
    u16* kvwb = Wb + 16384;

    k_prep<<<484, 256, 0, stream>>>(F, qw, kvw, ow, lnw, lnb, Xt, Wb, MuRs, Pml);
    k_gemm_kv<<<dim3(45, 4), 256, 0, stream>>>(Pml, kvwb, kvb, KVh, VTg);
    k_attn_fused<<<576, 512, 0, stream>>>(F, Xt, MuRs, KVh, VTg, Wb,
                                          qb, kvb, ob, Out);
}